// Round 1
// baseline (177.508 us; speedup 1.0000x reference)
//
#include <hip/hip_runtime.h>
#include <hip/hip_bf16.h>
#include <stdint.h>

// Problem constants: B=4, S=2048, D=512, H=8, DEPTH=64
#define B_ 4
#define S_ 2048
#define D_ 512
#define H_ 8

typedef __attribute__((ext_vector_type(8))) short short8;
typedef __attribute__((ext_vector_type(4))) float f32x4;

#define MFMA16(a,b,c) __builtin_amdgcn_mfma_f32_16x16x32_bf16((a),(b),(c),0,0,0)

__device__ __forceinline__ unsigned short f2bf(float f){
    return __builtin_bit_cast(unsigned short, __float2bfloat16(f));
}

__device__ __forceinline__ void gload_lds16(const void* g, void* l){
    __builtin_amdgcn_global_load_lds((const __attribute__((address_space(1))) uint32_t*)g,
                                     (__attribute__((address_space(3))) uint32_t*)l, 16, 0, 0);
}

// ---------------------------------------------------------------------------
// Prep 1: pack mask int32 [B][S][S] -> bits [B][S][S/32] (bit=1 means masked)
// ---------------------------------------------------------------------------
__global__ __launch_bounds__(256) void maskpack_kernel(const int* __restrict__ mask,
                                                       uint32_t* __restrict__ out)
{
    int idx = blockIdx.x*256 + threadIdx.x;            // 0 .. B*S*64-1
    const int4* p = (const int4*)(mask + (size_t)idx*32);
    uint32_t bits = 0;
    #pragma unroll
    for (int c=0;c<8;c++){
        int4 v = p[c];
        if (v.x) bits |= 1u << (c*4+0);
        if (v.y) bits |= 1u << (c*4+1);
        if (v.z) bits |= 1u << (c*4+2);
        if (v.w) bits |= 1u << (c*4+3);
    }
    out[idx] = bits;
}

// ---------------------------------------------------------------------------
// Prep 2: WT[mat][n][k] = W[mat][k][n] as bf16 (mats: wq,wk,wv,wo)
// ---------------------------------------------------------------------------
__global__ __launch_bounds__(256) void wtrans_kernel(const float* __restrict__ wq,
                                                     const float* __restrict__ wk,
                                                     const float* __restrict__ wv,
                                                     const float* __restrict__ wo,
                                                     unsigned short* __restrict__ wt)
{
    int f = blockIdx.x*256 + threadIdx.x;              // 0 .. 4*512*512-1
    int mat = f >> 18;
    int rem = f & 262143;
    const float* Wm = (mat==0)?wq:(mat==1)?wk:(mat==2)?wv:wo;
    int kk = rem >> 9, nn = rem & 511;                 // coalesced read of W[k][n]
    wt[(size_t)mat*262144 + (size_t)nn*512 + kk] = f2bf(Wm[rem]);
}

// ---------------------------------------------------------------------------
// Q/K/V projection: X(fp32 [8192][512]) @ W + b -> bf16 [B][H][S][64]
// 128x128 tile, BK=32, 4 waves in 2x2, 16 MFMAs/k-step. Q pre-scaled by
// 0.125*log2(e) so attention works directly in the exp2 domain.
// ---------------------------------------------------------------------------
__global__ __launch_bounds__(256) void proj_kernel(
    const float* __restrict__ q, const float* __restrict__ k, const float* __restrict__ v,
    const float* __restrict__ bq, const float* __restrict__ bk, const float* __restrict__ bv,
    const unsigned short* __restrict__ wt, unsigned short* __restrict__ outb)
{
    __shared__ uint8_t smem[16384];                    // A: [0,8K), B: [8K,16K)
    const int t = threadIdx.x, l = t&63, w = t>>6, g = l>>4, ln = l&15;
    const int z = blockIdx.z;
    const float* X = (z==0)? q : (z==1)? k : v;
    const float* bias = (z==0)? bq : (z==1)? bk : bv;
    const unsigned short* WTz = wt + (size_t)z*(D_*D_);
    unsigned short* out = outb + (size_t)z*((size_t)B_*H_*S_*64);
    const float scale = (z==0)? 0.18033688011112042f : 1.0f;  // 0.125*log2(e) for Q
    const int m0 = blockIdx.x*128, n0 = blockIdx.y*128;
    uint8_t* As = smem; uint8_t* Bs = smem + 8192;
    const int RB = (w>>1)*64, CB = (w&1)*64;

    const f32x4 zz = {0.f,0.f,0.f,0.f};
    f32x4 acc[4][4];
    #pragma unroll
    for (int i=0;i<4;i++)
        #pragma unroll
        for (int j=0;j<4;j++) acc[i][j] = zz;

    for (int k0=0; k0<D_; k0+=32){
        __syncthreads();
        // stage WT tile [128 n][32 k] via global_load_lds, pre-swizzled source
        #pragma unroll
        for (int i=0;i<2;i++){
            int qc = w + i*4;
            int row = qc*16 + (l>>2);
            int colb = ((l&3)*16) ^ ((row&3)<<4);
            gload_lds16((const uint8_t*)WTz + (((size_t)(n0+row)*D_ + k0)<<1) + colb,
                        Bs + qc*1024);
        }
        // stage X tile [128 m][32 k] fp32->bf16 via regs, swizzled ds_write_b128
        #pragma unroll
        for (int i=0;i<2;i++){
            int c = t + i*256;
            int row = c>>2, cc = c&3;
            const float4* src = (const float4*)(X + (size_t)(m0+row)*D_ + k0 + cc*8);
            float4 u0 = src[0], u1 = src[1];
            short8 pk;
            pk[0]=(short)f2bf(u0.x); pk[1]=(short)f2bf(u0.y);
            pk[2]=(short)f2bf(u0.z); pk[3]=(short)f2bf(u0.w);
            pk[4]=(short)f2bf(u1.x); pk[5]=(short)f2bf(u1.y);
            pk[6]=(short)f2bf(u1.z); pk[7]=(short)f2bf(u1.w);
            *(short8*)(As + row*64 + ((cc*16) ^ ((row&3)<<4))) = pk;
        }
        __syncthreads();
        short8 af[4], bfr[4];
        #pragma unroll
        for (int ai=0; ai<4; ai++){
            int row = RB + 16*ai + ln;
            af[ai] = *(const short8*)(As + row*64 + ((16*g) ^ ((row&3)<<4)));
        }
        #pragma unroll
        for (int bj=0; bj<4; bj++){
            int row = CB + 16*bj + ln;
            bfr[bj] = *(const short8*)(Bs + row*64 + ((16*g) ^ ((row&3)<<4)));
        }
        #pragma unroll
        for (int ai=0; ai<4; ai++)
            #pragma unroll
            for (int bj=0; bj<4; bj++)
                acc[ai][bj] = MFMA16(af[ai], bfr[bj], acc[ai][bj]);
    }

    // epilogue: bias, scale, write split-head bf16 [B][H][S][64]
    #pragma unroll
    for (int bj=0; bj<4; bj++){
        int gn = n0 + CB + 16*bj + ln;
        float bv2 = bias[gn];
        int h = gn >> 6, dep = gn & 63;
        #pragma unroll
        for (int ai=0; ai<4; ai++){
            #pragma unroll
            for (int r=0;r<4;r++){
                int gm = m0 + RB + 16*ai + 4*g + r;
                float val = (acc[ai][bj][r] + bv2) * scale;
                size_t o = ((size_t)(gm>>11)*H_ + h)*((size_t)S_*64) + (size_t)(gm&2047)*64 + dep;
                out[o] = f2bf(val);
            }
        }
    }
}

// ---------------------------------------------------------------------------
// Flash attention: per block (q-block 64 rows, one (b,h)). 4 waves x 16 rows.
// KV tile 64. Scores computed in log2 domain (Q pre-scaled). Bit-packed mask.
// ---------------------------------------------------------------------------
__global__ __launch_bounds__(256) void attn_kernel(
    const unsigned short* __restrict__ qb, const unsigned short* __restrict__ kb,
    const unsigned short* __restrict__ vb, const uint32_t* __restrict__ mb,
    unsigned short* __restrict__ ao)
{
    __shared__ uint8_t smem[24576];   // K:0..8K, VT:8K..16K, P: per-wave 2K at 16K..24K
    const int t = threadIdx.x, l = t&63, w = t>>6, g = l>>4, ln = l&15;
    const int bh = blockIdx.y;
    const int b = bh >> 3;
    const int q0 = blockIdx.x * 64;
    const unsigned short* Q = qb + (size_t)bh*((size_t)S_*64);
    const unsigned short* K = kb + (size_t)bh*((size_t)S_*64);
    const unsigned short* V = vb + (size_t)bh*((size_t)S_*64);
    uint8_t* Ks  = smem;
    uint8_t* VTs = smem + 8192;
    uint8_t* Ps  = smem + 16384 + w*2048;

    // Q fragments (A-operand), held in registers for the whole kernel
    short8 qf[2];
    {
        int row = q0 + 16*w + ln;
        qf[0] = *(const short8*)(Q + (size_t)row*64 + 8*g);
        qf[1] = *(const short8*)(Q + (size_t)row*64 + 8*g + 32);
    }

    const f32x4 zz = {0.f,0.f,0.f,0.f};
    f32x4 O[4]; 
    #pragma unroll
    for (int i=0;i<4;i++) O[i] = zz;
    float m[4], lsum[4];
    #pragma unroll
    for (int r=0;r<4;r++){ m[r] = -1e30f; lsum[r] = 0.f; }

    const uint32_t* mrow[4];
    #pragma unroll
    for (int r=0;r<4;r++)
        mrow[r] = mb + ((size_t)b*S_ + (q0 + 16*w + 4*g + r))*64;

    for (int it=0; it<S_/64; ++it){
        int kv0 = it*64;
        __syncthreads();   // protect K/VT reuse from previous iteration's reads

        // stage K tile [64][64] bf16 via global_load_lds (pre-swizzled source)
        #pragma unroll
        for (int i=0;i<2;i++){
            int qc = w + i*4;
            int row = qc*8 + (l>>3);
            int colb = ((l&7)*16) ^ ((row&7)<<4);
            gload_lds16((const uint8_t*)K + ((size_t)(kv0+row)<<7) + colb, Ks + qc*1024);
        }
        // stage V transposed: VT[d][kv], swizzled, packed u32 writes (conflict-free)
        {
            int a = l & 31;
            int d0 = 16*w + 8*(l>>5);
            const uint8_t* vsrc = (const uint8_t*)V + ((size_t)(kv0 + 2*a)<<7) + d0*2;
            short8 v0 = *(const short8*)(vsrc);
            short8 v1 = *(const short8*)(vsrc + 128);
            #pragma unroll
            for (int j=0;j<8;j++){
                int d = d0 + j;
                uint32_t pk = (uint32_t)(unsigned short)v0[j] | ((uint32_t)(unsigned short)v1[j] << 16);
                *(uint32_t*)(VTs + d*128 + ((4*a) ^ ((d&7)<<4))) = pk;
            }
        }
        // prefetch mask bit-words (latency hidden by the barrier)
        uint32_t mw[4][2];
        #pragma unroll
        for (int r=0;r<4;r++){
            mw[r][0] = mrow[r][2*it];
            mw[r][1] = mrow[r][2*it+1];
        }
        __syncthreads();

        // scores: S^ = Q.K^T (log2-domain), 4 column-blocks of 16
        f32x4 s[4];
        #pragma unroll
        for (int t4=0;t4<4;t4++) s[t4] = zz;
        #pragma unroll
        for (int t4=0;t4<4;t4++){
            int row = t4*16 + ln;
            short8 kf0 = *(const short8*)(Ks + row*128 + ((16*g      ) ^ ((row&7)<<4)));
            short8 kf1 = *(const short8*)(Ks + row*128 + ((16*g + 64 ) ^ ((row&7)<<4)));
            s[t4] = MFMA16(qf[0], kf0, s[t4]);
            s[t4] = MFMA16(qf[1], kf1, s[t4]);
        }

        // mask + online softmax (lane holds col kj=t4*16+ln, rows qi=4g+r)
        float mnew[4], alpha[4];
        #pragma unroll
        for (int r=0;r<4;r++){
            float rmax = -3e38f;
            #pragma unroll
            for (int t4=0;t4<4;t4++){
                uint32_t wbits = mw[r][t4>>1];
                int bit = (wbits >> (((t4&1)<<4) + ln)) & 1;
                float sv = s[t4][r];
                sv = bit ? sv - 1e9f : sv;
                s[t4][r] = sv;
                rmax = fmaxf(rmax, sv);
            }
            rmax = fmaxf(rmax, __shfl_xor(rmax, 1));
            rmax = fmaxf(rmax, __shfl_xor(rmax, 2));
            rmax = fmaxf(rmax, __shfl_xor(rmax, 4));
            rmax = fmaxf(rmax, __shfl_xor(rmax, 8));
            mnew[r] = fmaxf(m[r], rmax);
            alpha[r] = __builtin_amdgcn_exp2f(m[r] - mnew[r]);
            m[r] = mnew[r];
        }
        // p = exp2(s - m), row sums, write P tile (per-wave LDS, swizzled)
        #pragma unroll
        for (int r=0;r<4;r++){
            float psum = 0.f;
            int prow = 4*g + r;
            #pragma unroll
            for (int t4=0;t4<4;t4++){
                float p = __builtin_amdgcn_exp2f(s[t4][r] - mnew[r]);
                psum += p;
                int kj = t4*16 + ln;
                *(unsigned short*)(Ps + prow*128 + ((2*kj) ^ ((prow&7)<<4))) = f2bf(p);
            }
            psum += __shfl_xor(psum, 1);
            psum += __shfl_xor(psum, 2);
            psum += __shfl_xor(psum, 4);
            psum += __shfl_xor(psum, 8);
            lsum[r] = lsum[r]*alpha[r] + psum;
        }
        // rescale O accumulators
        #pragma unroll
        for (int db=0; db<4; db++)
            #pragma unroll
            for (int r=0;r<4;r++) O[db][r] *= alpha[r];

        // wave-local LDS write->read fence (no barrier needed: per-wave region)
        asm volatile("s_waitcnt lgkmcnt(0)" ::: "memory");

        // PV: O += P @ V
        short8 pa0, pa1;
        {
            int prow = ln;
            pa0 = *(const short8*)(Ps + prow*128 + ((16*g     ) ^ ((prow&7)<<4)));
            pa1 = *(const short8*)(Ps + prow*128 + ((16*g + 64) ^ ((prow&7)<<4)));
        }
        #pragma unroll
        for (int db=0; db<4; db++){
            int drow = 16*db + ln;
            short8 vf0 = *(const short8*)(VTs + drow*128 + ((16*g     ) ^ ((drow&7)<<4)));
            short8 vf1 = *(const short8*)(VTs + drow*128 + ((16*g + 64) ^ ((drow&7)<<4)));
            O[db] = MFMA16(pa0, vf0, O[db]);
            O[db] = MFMA16(pa1, vf1, O[db]);
        }
    }

    // normalize and write merged-head bf16 [B*S][512]
    #pragma unroll
    for (int r=0;r<4;r++){
        float inv = 1.0f / lsum[r];
        int gm = b*S_ + q0 + 16*w + 4*g + r;
        #pragma unroll
        for (int db=0; db<4; db++){
            int col = (bh&7)*64 + 16*db + ln;
            ao[(size_t)gm*D_ + col] = f2bf(O[db][r]*inv);
        }
    }
}

// ---------------------------------------------------------------------------
// Output projection: ao(bf16 [8192][512]) @ wo + bo -> fp32 out
// ---------------------------------------------------------------------------
__global__ __launch_bounds__(256) void outproj_kernel(
    const unsigned short* __restrict__ ao, const unsigned short* __restrict__ wt,
    const float* __restrict__ bo, float* __restrict__ out)
{
    __shared__ uint8_t smem[16384];
    const int t = threadIdx.x, l = t&63, w = t>>6, g = l>>4, ln = l&15;
    const unsigned short* WTz = wt + (size_t)3*(D_*D_);
    const int m0 = blockIdx.x*128, n0 = blockIdx.y*128;
    uint8_t* As = smem; uint8_t* Bs = smem + 8192;
    const int RB = (w>>1)*64, CB = (w&1)*64;

    const f32x4 zz = {0.f,0.f,0.f,0.f};
    f32x4 acc[4][4];
    #pragma unroll
    for (int i=0;i<4;i++)
        #pragma unroll
        for (int j=0;j<4;j++) acc[i][j] = zz;

    for (int k0=0; k0<D_; k0+=32){
        __syncthreads();
        #pragma unroll
        for (int i=0;i<2;i++){
            int qc = w + i*4;
            int row = qc*16 + (l>>2);
            int colb = ((l&3)*16) ^ ((row&3)<<4);
            gload_lds16((const uint8_t*)WTz + (((size_t)(n0+row)*D_ + k0)<<1) + colb,
                        Bs + qc*1024);
            gload_lds16((const uint8_t*)ao + (((size_t)(m0+row)*D_ + k0)<<1) + colb,
                        As + qc*1024);
        }
        __syncthreads();
        short8 af[4], bfr[4];
        #pragma unroll
        for (int ai=0; ai<4; ai++){
            int row = RB + 16*ai + ln;
            af[ai] = *(const short8*)(As + row*64 + ((16*g) ^ ((row&3)<<4)));
        }
        #pragma unroll
        for (int bj=0; bj<4; bj++){
            int row = CB + 16*bj + ln;
            bfr[bj] = *(const short8*)(Bs + row*64 + ((16*g) ^ ((row&3)<<4)));
        }
        #pragma unroll
        for (int ai=0; ai<4; ai++)
            #pragma unroll
            for (int bj=0; bj<4; bj++)
                acc[ai][bj] = MFMA16(af[ai], bfr[bj], acc[ai][bj]);
    }

    #pragma unroll
    for (int bj=0; bj<4; bj++){
        int gn = n0 + CB + 16*bj + ln;
        float bv2 = bo[gn];
        #pragma unroll
        for (int ai=0; ai<4; ai++){
            #pragma unroll
            for (int r=0;r<4;r++){
                int gm = m0 + RB + 16*ai + 4*g + r;
                out[(size_t)gm*D_ + gn] = acc[ai][bj][r] + bv2;
            }
        }
    }
}

// ---------------------------------------------------------------------------
extern "C" void kernel_launch(void* const* d_in, const int* in_sizes, int n_in,
                              void* d_out, int out_size, void* d_ws, size_t ws_size,
                              hipStream_t stream)
{
    const float* q  = (const float*)d_in[0];
    const float* k  = (const float*)d_in[1];
    const float* v  = (const float*)d_in[2];
    const int* mask = (const int*)d_in[3];
    const float* wq = (const float*)d_in[4];
    const float* bq = (const float*)d_in[5];
    const float* wk = (const float*)d_in[6];
    const float* bk = (const float*)d_in[7];
    const float* wv = (const float*)d_in[8];
    const float* bv = (const float*)d_in[9];
    const float* wo = (const float*)d_in[10];
    const float* bo = (const float*)d_in[11];

    uint8_t* ws = (uint8_t*)d_ws;
    // ws layout (bytes):
    //   0        : qb/kb/vb bf16 [3][B*H*S*64]      (3 * 8388608)
    //   25165824 : ao bf16 [8192][512]              (8388608)
    //   33554432 : WT bf16 [4][512][512]            (2097152)
    //   35651584 : mask bits u32 [B*S*64]           (2097152)
    unsigned short* qkvb = (unsigned short*)ws;
    unsigned short* ao   = (unsigned short*)(ws + 25165824);
    unsigned short* wt   = (unsigned short*)(ws + 33554432);
    uint32_t*       mb   = (uint32_t*)      (ws + 35651584);
    float* out = (float*)d_out;

    maskpack_kernel<<<dim3(2048), dim3(256), 0, stream>>>(mask, mb);
    wtrans_kernel<<<dim3(4096), dim3(256), 0, stream>>>(wq, wk, wv, wo, wt);
    proj_kernel<<<dim3(64,4,3), dim3(256), 0, stream>>>(q, k, v, bq, bk, bv, wt, qkvb);
    attn_kernel<<<dim3(32,32), dim3(256), 0, stream>>>(qkvb, qkvb + 4194304, qkvb + 8388608, mb, ao);
    outproj_kernel<<<dim3(64,4), dim3(256), 0, stream>>>(ao, wt, bo, out);
}

// Round 3
// 146.176 us; speedup vs baseline: 1.2143x; 1.2143x over previous
//
#include <hip/hip_runtime.h>
#include <hip/hip_bf16.h>
#include <stdint.h>

// Problem constants: B=4, S=2048, D=512, H=8, DEPTH=64
#define B_ 4
#define S_ 2048
#define D_ 512
#define H_ 8

typedef __attribute__((ext_vector_type(8))) short short8;
typedef __attribute__((ext_vector_type(4))) float f32x4;
typedef __attribute__((ext_vector_type(4))) unsigned short u16x4;

#define MFMA16(a,b,c) __builtin_amdgcn_mfma_f32_16x16x32_bf16((a),(b),(c),0,0,0)

__device__ __forceinline__ unsigned short f2bf(float f){
    return __builtin_bit_cast(unsigned short, __float2bfloat16(f));
}

__device__ __forceinline__ float maskf(float p, uint32_t keep){
    return __builtin_bit_cast(float, __builtin_bit_cast(uint32_t, p) & keep);
}

__device__ __forceinline__ void gload_lds16(const void* g, void* l){
    __builtin_amdgcn_global_load_lds((const __attribute__((address_space(1))) uint32_t*)g,
                                     (__attribute__((address_space(3))) uint32_t*)l, 16, 0, 0);
}

// ---------------------------------------------------------------------------
// Prep 1: pack mask int32 [B][S][S] -> bits [B][S][S/32] (bit=1 means masked)
// ---------------------------------------------------------------------------
__global__ __launch_bounds__(256) void maskpack_kernel(const int* __restrict__ mask,
                                                       uint32_t* __restrict__ out)
{
    int idx = blockIdx.x*256 + threadIdx.x;            // 0 .. B*S*64-1
    const int4* p = (const int4*)(mask + (size_t)idx*32);
    uint32_t bits = 0;
    #pragma unroll
    for (int c=0;c<8;c++){
        int4 v = p[c];
        if (v.x) bits |= 1u << (c*4+0);
        if (v.y) bits |= 1u << (c*4+1);
        if (v.z) bits |= 1u << (c*4+2);
        if (v.w) bits |= 1u << (c*4+3);
    }
    out[idx] = bits;
}

// ---------------------------------------------------------------------------
// Prep 2: WT[mat][n][k] = W[mat][k][n] as bf16 (mats: wq,wk,wv,wo)
// ---------------------------------------------------------------------------
__global__ __launch_bounds__(256) void wtrans_kernel(const float* __restrict__ wq,
                                                     const float* __restrict__ wk,
                                                     const float* __restrict__ wv,
                                                     const float* __restrict__ wo,
                                                     unsigned short* __restrict__ wt)
{
    int f = blockIdx.x*256 + threadIdx.x;              // 0 .. 4*512*512-1
    int mat = f >> 18;
    int rem = f & 262143;
    const float* Wm = (mat==0)?wq:(mat==1)?wk:(mat==2)?wv:wo;
    int kk = rem >> 9, nn = rem & 511;                 // coalesced read of W[k][n]
    wt[(size_t)mat*262144 + (size_t)nn*512 + kk] = f2bf(Wm[rem]);
}

// ---------------------------------------------------------------------------
// Q/K/V projection: X(fp32 [8192][512]) @ W + b.
// z=0 (Q): bf16 [B][H][S][64], pre-scaled by 0.125*log2(e) (exp2 domain).
// z=1 (K): bf16 [B][H][S][64].
// z=2 (V): TRANSPOSED bf16 VT [B][H][64][S]  (so attn can global_load_lds it).
// ---------------------------------------------------------------------------
__global__ __launch_bounds__(256) void proj_kernel(
    const float* __restrict__ q, const float* __restrict__ k, const float* __restrict__ v,
    const float* __restrict__ bq, const float* __restrict__ bk, const float* __restrict__ bv,
    const unsigned short* __restrict__ wt, unsigned short* __restrict__ outb)
{
    __shared__ uint8_t smem[16384];                    // A: [0,8K), B: [8K,16K)
    const int t = threadIdx.x, l = t&63, w = t>>6, g = l>>4, ln = l&15;
    const int z = blockIdx.z;
    const float* X = (z==0)? q : (z==1)? k : v;
    const float* bias = (z==0)? bq : (z==1)? bk : bv;
    const unsigned short* WTz = wt + (size_t)z*(D_*D_);
    unsigned short* out = outb + (size_t)z*((size_t)B_*H_*S_*64);
    const float scale = (z==0)? 0.18033688011112042f : 1.0f;  // 0.125*log2(e) for Q
    const int m0 = blockIdx.x*128, n0 = blockIdx.y*128;
    uint8_t* As = smem; uint8_t* Bs = smem + 8192;
    const int RB = (w>>1)*64, CB = (w&1)*64;

    const f32x4 zz = {0.f,0.f,0.f,0.f};
    f32x4 acc[4][4];
    #pragma unroll
    for (int i=0;i<4;i++)
        #pragma unroll
        for (int j=0;j<4;j++) acc[i][j] = zz;

    for (int k0=0; k0<D_; k0+=32){
        __syncthreads();
        // stage WT tile [128 n][32 k] via global_load_lds, pre-swizzled source
        #pragma unroll
        for (int i=0;i<2;i++){
            int qc = w + i*4;
            int row = qc*16 + (l>>2);
            int colb = ((l&3)*16) ^ ((row&3)<<4);
            gload_lds16((const uint8_t*)WTz + (((size_t)(n0+row)*D_ + k0)<<1) + colb,
                        Bs + qc*1024);
        }
        // stage X tile [128 m][32 k] fp32->bf16 via regs, swizzled ds_write_b128
        #pragma unroll
        for (int i=0;i<2;i++){
            int c = t + i*256;
            int row = c>>2, cc = c&3;
            const float4* src = (const float4*)(X + (size_t)(m0+row)*D_ + k0 + cc*8);
            float4 u0 = src[0], u1 = src[1];
            short8 pk;
            pk[0]=(short)f2bf(u0.x); pk[1]=(short)f2bf(u0.y);
            pk[2]=(short)f2bf(u0.z); pk[3]=(short)f2bf(u0.w);
            pk[4]=(short)f2bf(u1.x); pk[5]=(short)f2bf(u1.y);
            pk[6]=(short)f2bf(u1.z); pk[7]=(short)f2bf(u1.w);
            *(short8*)(As + row*64 + ((cc*16) ^ ((row&3)<<4))) = pk;
        }
        __syncthreads();
        short8 af[4], bfr[4];
        #pragma unroll
        for (int ai=0; ai<4; ai++){
            int row = RB + 16*ai + ln;
            af[ai] = *(const short8*)(As + row*64 + ((16*g) ^ ((row&3)<<4)));
        }
        #pragma unroll
        for (int bj=0; bj<4; bj++){
            int row = CB + 16*bj + ln;
            bfr[bj] = *(const short8*)(Bs + row*64 + ((16*g) ^ ((row&3)<<4)));
        }
        #pragma unroll
        for (int ai=0; ai<4; ai++)
            #pragma unroll
            for (int bj=0; bj<4; bj++)
                acc[ai][bj] = MFMA16(af[ai], bfr[bj], acc[ai][bj]);
    }

    if (z == 2){
        // V: write transposed VT[b][gn][s], pack 4 consecutive s (r=0..3) per b64
        #pragma unroll
        for (int bj=0; bj<4; bj++){
            int gn = n0 + CB + 16*bj + ln;           // = h*64 + dep
            float bv2 = bias[gn];
            #pragma unroll
            for (int ai=0; ai<4; ai++){
                int gmb = m0 + RB + 16*ai + 4*g;     // r=0 row
                int bidx = gmb >> 11, s = gmb & 2047;
                u16x4 pk;
                #pragma unroll
                for (int r=0;r<4;r++) pk[r] = f2bf(acc[ai][bj][r] + bv2);
                *(u16x4*)(out + ((size_t)bidx*D_ + gn)*S_ + s) = pk;
            }
        }
    } else {
        // Q/K: bias, scale, write split-head bf16 [B][H][S][64]
        #pragma unroll
        for (int bj=0; bj<4; bj++){
            int gn = n0 + CB + 16*bj + ln;
            float bv2 = bias[gn];
            int h = gn >> 6, dep = gn & 63;
            #pragma unroll
            for (int ai=0; ai<4; ai++){
                #pragma unroll
                for (int r=0;r<4;r++){
                    int gm = m0 + RB + 16*ai + 4*g + r;
                    float val = (acc[ai][bj][r] + bv2) * scale;
                    size_t o = ((size_t)(gm>>11)*H_ + h)*((size_t)S_*64) + (size_t)(gm&2047)*64 + dep;
                    out[o] = f2bf(val);
                }
            }
        }
    }
}

// ---------------------------------------------------------------------------
// Flash attention v2: swapped QK^T (in-register softmax), double-buffered
// K/VT staging via global_load_lds, defer-max, b64 P writes via cvt_pk.
// Block = 64 q-rows (4 waves x 16), one (b,h). KV tile 64.
// LDS layout (byte offsets): K dbuf [0,8K)+[8K,16K), VT dbuf [16K,24K)+[24K,32K),
// P per-wave [32K + w*2K, ...). Buffer select via integer offsets (no LDS
// pointer arrays — those fail to compile on hipcc).
// ---------------------------------------------------------------------------
__global__ __launch_bounds__(256) void attn_kernel(
    const unsigned short* __restrict__ qb, const unsigned short* __restrict__ kb,
    const unsigned short* __restrict__ vtb, const uint32_t* __restrict__ mb,
    unsigned short* __restrict__ ao)
{
    __shared__ uint8_t smem[40960];
    const int t = threadIdx.x, l = t&63, w = t>>6, g = l>>4, ln = l&15;
    const int bh = blockIdx.y;
    const int b = bh >> 3;
    const int q0 = blockIdx.x * 64;
    const unsigned short* Q  = qb + (size_t)bh*((size_t)S_*64);
    const unsigned short* K  = kb + (size_t)bh*((size_t)S_*64);
    const unsigned short* VT = vtb + ((size_t)b*D_ + (bh&7)*64)*S_;

    uint8_t* Ps = smem + 32768 + w*2048;

    // Q fragments (held all kernel); q row for this lane = q0+16w+ln
    const int qrow = q0 + 16*w + ln;
    const short8 qf0 = *(const short8*)(Q + (size_t)qrow*64 + 8*g);
    const short8 qf1 = *(const short8*)(Q + (size_t)qrow*64 + 8*g + 32);

    // per-lane pre-swizzled staging sources (advance per iter)
    const uint8_t* ksrc0; const uint8_t* ksrc1;
    const uint8_t* vsrc0; const uint8_t* vsrc1;
    int ldoff0, ldoff1;
    {
        int qc0 = w, qc1 = w + 4;
        int row0 = qc0*8 + (l>>3), row1 = qc1*8 + (l>>3);
        int colb0 = ((l&7)*16) ^ ((row0&7)<<4);
        int colb1 = ((l&7)*16) ^ ((row1&7)<<4);
        ksrc0 = (const uint8_t*)K  + (size_t)row0*128    + colb0;
        ksrc1 = (const uint8_t*)K  + (size_t)row1*128    + colb1;
        vsrc0 = (const uint8_t*)VT + (size_t)row0*(S_*2) + colb0;
        vsrc1 = (const uint8_t*)VT + (size_t)row1*(S_*2) + colb1;
        ldoff0 = qc0*1024; ldoff1 = qc1*1024;
    }
    const uint2* mptr = (const uint2*)(mb + ((size_t)b*S_ + qrow)*64);

    const f32x4 zz = {0.f,0.f,0.f,0.f};
    f32x4 O[4];
    #pragma unroll
    for (int i=0;i<4;i++) O[i] = zz;
    float m = -1e30f, lsum = 0.f;

    // prologue: stage tile 0 into buffer 0
    gload_lds16(ksrc0, smem + ldoff0);
    gload_lds16(ksrc1, smem + ldoff1);
    gload_lds16(vsrc0, smem + 16384 + ldoff0);
    gload_lds16(vsrc1, smem + 16384 + ldoff1);
    ksrc0 += 8192; ksrc1 += 8192; vsrc0 += 128; vsrc1 += 128;
    int curb = 0;   // byte offset of current buffer (0 or 8192)

    for (int it=0; it<S_/64; ++it){
        __syncthreads();   // staged tile [cur] ready; prev reads of [cur^1] done
        if (it < S_/64 - 1){
            int nx = curb ^ 8192;
            gload_lds16(ksrc0, smem + nx + ldoff0);
            gload_lds16(ksrc1, smem + nx + ldoff1);
            gload_lds16(vsrc0, smem + 16384 + nx + ldoff0);
            gload_lds16(vsrc1, smem + 16384 + nx + ldoff1);
            ksrc0 += 8192; ksrc1 += 8192; vsrc0 += 128; vsrc1 += 128;
        }
        const uint2 mm = mptr[it];
        uint8_t* Ks  = smem + curb;
        uint8_t* VTs = smem + 16384 + curb;

        // ST = K @ Q^T  -> ST[kv][q]: lane holds q=ln, kv=16*t4+4*g+r
        f32x4 st[4];
        __builtin_amdgcn_s_setprio(1);
        #pragma unroll
        for (int t4=0;t4<4;t4++){
            int row = t4*16 + ln;
            short8 kf0 = *(const short8*)(Ks + row*128 + ((16*g     ) ^ ((row&7)<<4)));
            short8 kf1 = *(const short8*)(Ks + row*128 + ((16*g + 64) ^ ((row&7)<<4)));
            st[t4] = MFMA16(kf0, qf0, zz);
            st[t4] = MFMA16(kf1, qf1, st[t4]);
        }
        __builtin_amdgcn_s_setprio(0);

        // row max over raw scores (masked entries only shift the common scale)
        float rmax;
        {
            float a0 = fmaxf(fmaxf(st[0][0],st[0][1]), fmaxf(st[0][2],st[0][3]));
            float a1 = fmaxf(fmaxf(st[1][0],st[1][1]), fmaxf(st[1][2],st[1][3]));
            float a2 = fmaxf(fmaxf(st[2][0],st[2][1]), fmaxf(st[2][2],st[2][3]));
            float a3 = fmaxf(fmaxf(st[3][0],st[3][1]), fmaxf(st[3][2],st[3][3]));
            rmax = fmaxf(fmaxf(a0,a1), fmaxf(a2,a3));
            rmax = fmaxf(rmax, __shfl_xor(rmax, 16));
            rmax = fmaxf(rmax, __shfl_xor(rmax, 32));
        }
        // defer-max (THR=8 in exp2 domain): rescale only when max grows enough
        if (__any(rmax > m + 8.0f)){
            float mnew = fmaxf(m, rmax);
            float alpha = __builtin_amdgcn_exp2f(m - mnew);
            m = mnew;
            lsum *= alpha;
            #pragma unroll
            for (int r=0;r<4;r++){
                float aO = __shfl(alpha, 4*g + r);
                #pragma unroll
                for (int db=0; db<4; db++) O[db][r] *= aO;
            }
        }

        // p = exp2(s-m), zero masked, row-sum, pack to bf16, b64 P writes
        uint32_t mi0 = (~mm.x) >> (4*g);
        uint32_t mi1 = (~mm.y) >> (4*g);
        float psum = 0.f;
        #pragma unroll
        for (int t4=0;t4<4;t4++){
            uint32_t mi = (t4 >= 2) ? mi1 : mi0;
            const int sh = (t4&1)*16;
            float p0, p1, p2, p3;
            {
                float pv = __builtin_amdgcn_exp2f(st[t4][0] - m);
                uint32_t keep = (uint32_t)(((int32_t)(mi << (31-(sh+0)))) >> 31);
                p0 = maskf(pv, keep);
                pv = __builtin_amdgcn_exp2f(st[t4][1] - m);
                keep = (uint32_t)(((int32_t)(mi << (31-(sh+1)))) >> 31);
                p1 = maskf(pv, keep);
                pv = __builtin_amdgcn_exp2f(st[t4][2] - m);
                keep = (uint32_t)(((int32_t)(mi << (31-(sh+2)))) >> 31);
                p2 = maskf(pv, keep);
                pv = __builtin_amdgcn_exp2f(st[t4][3] - m);
                keep = (uint32_t)(((int32_t)(mi << (31-(sh+3)))) >> 31);
                p3 = maskf(pv, keep);
            }
            psum += (p0 + p1) + (p2 + p3);
            uint32_t lo, hi;
            asm("v_cvt_pk_bf16_f32 %0, %1, %2" : "=v"(lo) : "v"(p0), "v"(p1));
            asm("v_cvt_pk_bf16_f32 %0, %1, %2" : "=v"(hi) : "v"(p2), "v"(p3));
            uint2 pk; pk.x = lo; pk.y = hi;
            *(uint2*)(Ps + ln*128 + ((32*t4 + 8*g) ^ ((ln&7)<<4))) = pk;
        }
        psum += __shfl_xor(psum, 16);
        psum += __shfl_xor(psum, 32);
        lsum += psum;

        // wave-local P write->read fence
        asm volatile("s_waitcnt lgkmcnt(0)" ::: "memory");

        short8 pa0 = *(const short8*)(Ps + ln*128 + ((16*g     ) ^ ((ln&7)<<4)));
        short8 pa1 = *(const short8*)(Ps + ln*128 + ((16*g + 64) ^ ((ln&7)<<4)));
        __builtin_amdgcn_s_setprio(1);
        #pragma unroll
        for (int db=0; db<4; db++){
            int dr = 16*db + ln;
            short8 vf0 = *(const short8*)(VTs + dr*128 + ((16*g     ) ^ ((dr&7)<<4)));
            short8 vf1 = *(const short8*)(VTs + dr*128 + ((16*g + 64) ^ ((dr&7)<<4)));
            O[db] = MFMA16(pa0, vf0, O[db]);
            O[db] = MFMA16(pa1, vf1, O[db]);
        }
        __builtin_amdgcn_s_setprio(0);
        curb ^= 8192;
    }

    // normalize and write merged-head bf16 [B*S][512]
    float inv = 1.0f / lsum;
    #pragma unroll
    for (int r=0;r<4;r++){
        float invO = __shfl(inv, 4*g + r);
        int gm = b*S_ + q0 + 16*w + 4*g + r;
        #pragma unroll
        for (int db=0; db<4; db++){
            int col = (bh&7)*64 + 16*db + ln;
            ao[(size_t)gm*D_ + col] = f2bf(O[db][r]*invO);
        }
    }
}

// ---------------------------------------------------------------------------
// Output projection: ao(bf16 [8192][512]) @ wo + bo -> fp32 out
// ---------------------------------------------------------------------------
__global__ __launch_bounds__(256) void outproj_kernel(
    const unsigned short* __restrict__ ao, const unsigned short* __restrict__ wt,
    const float* __restrict__ bo, float* __restrict__ out)
{
    __shared__ uint8_t smem[16384];
    const int t = threadIdx.x, l = t&63, w = t>>6, g = l>>4, ln = l&15;
    const unsigned short* WTz = wt + (size_t)3*(D_*D_);
    const int m0 = blockIdx.x*128, n0 = blockIdx.y*128;
    uint8_t* As = smem; uint8_t* Bs = smem + 8192;
    const int RB = (w>>1)*64, CB = (w&1)*64;

    const f32x4 zz = {0.f,0.f,0.f,0.f};
    f32x4 acc[4][4];
    #pragma unroll
    for (int i=0;i<4;i++)
        #pragma unroll
        for (int j=0;j<4;j++) acc[i][j] = zz;

    for (int k0=0; k0<D_; k0+=32){
        __syncthreads();
        #pragma unroll
        for (int i=0;i<2;i++){
            int qc = w + i*4;
            int row = qc*16 + (l>>2);
            int colb = ((l&3)*16) ^ ((row&3)<<4);
            gload_lds16((const uint8_t*)WTz + (((size_t)(n0+row)*D_ + k0)<<1) + colb,
                        Bs + qc*1024);
            gload_lds16((const uint8_t*)ao + (((size_t)(m0+row)*D_ + k0)<<1) + colb,
                        As + qc*1024);
        }
        __syncthreads();
        short8 af[4], bfr[4];
        #pragma unroll
        for (int ai=0; ai<4; ai++){
            int row = RB + 16*ai + ln;
            af[ai] = *(const short8*)(As + row*64 + ((16*g) ^ ((row&3)<<4)));
        }
        #pragma unroll
        for (int bj=0; bj<4; bj++){
            int row = CB + 16*bj + ln;
            bfr[bj] = *(const short8*)(Bs + row*64 + ((16*g) ^ ((row&3)<<4)));
        }
        #pragma unroll
        for (int ai=0; ai<4; ai++)
            #pragma unroll
            for (int bj=0; bj<4; bj++)
                acc[ai][bj] = MFMA16(af[ai], bfr[bj], acc[ai][bj]);
    }

    #pragma unroll
    for (int bj=0; bj<4; bj++){
        int gn = n0 + CB + 16*bj + ln;
        float bv2 = bo[gn];
        #pragma unroll
        for (int ai=0; ai<4; ai++){
            #pragma unroll
            for (int r=0;r<4;r++){
                int gm = m0 + RB + 16*ai + 4*g + r;
                out[(size_t)gm*D_ + gn] = acc[ai][bj][r] + bv2;
            }
        }
    }
}

// ---------------------------------------------------------------------------
extern "C" void kernel_launch(void* const* d_in, const int* in_sizes, int n_in,
                              void* d_out, int out_size, void* d_ws, size_t ws_size,
                              hipStream_t stream)
{
    const float* q  = (const float*)d_in[0];
    const float* k  = (const float*)d_in[1];
    const float* v  = (const float*)d_in[2];
    const int* mask = (const int*)d_in[3];
    const float* wq = (const float*)d_in[4];
    const float* bq = (const float*)d_in[5];
    const float* wk = (const float*)d_in[6];
    const float* bk = (const float*)d_in[7];
    const float* wv = (const float*)d_in[8];
    const float* bv = (const float*)d_in[9];
    const float* wo = (const float*)d_in[10];
    const float* bo = (const float*)d_in[11];

    uint8_t* ws = (uint8_t*)d_ws;
    // ws layout (bytes):
    //   0        : qb bf16 [B][H][S][64]            (8388608)
    //   8388608  : kb bf16 [B][H][S][64]            (8388608)
    //   16777216 : vt bf16 [B][H][64][S]            (8388608)
    //   25165824 : ao bf16 [8192][512]              (8388608)
    //   33554432 : WT bf16 [4][512][512]            (2097152)
    //   35651584 : mask bits u32 [B*S*64]           (2097152)
    unsigned short* qkvb = (unsigned short*)ws;
    unsigned short* ao   = (unsigned short*)(ws + 25165824);
    unsigned short* wt   = (unsigned short*)(ws + 33554432);
    uint32_t*       mb   = (uint32_t*)      (ws + 35651584);
    float* out = (float*)d_out;

    maskpack_kernel<<<dim3(2048), dim3(256), 0, stream>>>(mask, mb);
    wtrans_kernel<<<dim3(4096), dim3(256), 0, stream>>>(wq, wk, wv, wo, wt);
    proj_kernel<<<dim3(64,4,3), dim3(256), 0, stream>>>(q, k, v, bq, bk, bv, wt, qkvb);
    attn_kernel<<<dim3(32,32), dim3(256), 0, stream>>>(qkvb, qkvb + 4194304, qkvb + 8388608, mb, ao);
    outproj_kernel<<<dim3(64,4), dim3(256), 0, stream>>>(ao, wt, bo, out);
}

// Round 4
// 140.608 us; speedup vs baseline: 1.2624x; 1.0396x over previous
//
#include <hip/hip_runtime.h>
#include <hip/hip_bf16.h>
#include <stdint.h>

// Problem constants: B=4, S=2048, D=512, H=8, DEPTH=64
#define B_ 4
#define S_ 2048
#define D_ 512
#define H_ 8

typedef __attribute__((ext_vector_type(8))) short short8;
typedef __attribute__((ext_vector_type(4))) float f32x4;
typedef __attribute__((ext_vector_type(4))) unsigned short u16x4;

#define MFMA16(a,b,c) __builtin_amdgcn_mfma_f32_16x16x32_bf16((a),(b),(c),0,0,0)

__device__ __forceinline__ unsigned short f2bf(float f){
    return __builtin_bit_cast(unsigned short, __float2bfloat16(f));
}

__device__ __forceinline__ float maskf(float p, uint32_t keep){
    return __builtin_bit_cast(float, __builtin_bit_cast(uint32_t, p) & keep);
}

__device__ __forceinline__ float max3f(float a, float b, float c){
    float d;
    asm("v_max3_f32 %0, %1, %2, %3" : "=v"(d) : "v"(a), "v"(b), "v"(c));
    return d;
}

__device__ __forceinline__ void gload_lds16(const void* g, void* l){
    __builtin_amdgcn_global_load_lds((const __attribute__((address_space(1))) uint32_t*)g,
                                     (__attribute__((address_space(3))) uint32_t*)l, 16, 0, 0);
}

// ---------------------------------------------------------------------------
// Prep 1: pack mask int32 [B][S][S] -> bits [B][S][S/32] (bit=1 means masked)
// ---------------------------------------------------------------------------
__global__ __launch_bounds__(256) void maskpack_kernel(const int* __restrict__ mask,
                                                       uint32_t* __restrict__ out)
{
    int idx = blockIdx.x*256 + threadIdx.x;            // 0 .. B*S*64-1
    const int4* p = (const int4*)(mask + (size_t)idx*32);
    uint32_t bits = 0;
    #pragma unroll
    for (int c=0;c<8;c++){
        int4 v = p[c];
        if (v.x) bits |= 1u << (c*4+0);
        if (v.y) bits |= 1u << (c*4+1);
        if (v.z) bits |= 1u << (c*4+2);
        if (v.w) bits |= 1u << (c*4+3);
    }
    out[idx] = bits;
}

// ---------------------------------------------------------------------------
// Prep 2: WT[mat][n][k] = W[mat][k][n] as bf16. Coalesced 16B writes,
// scattered 4B reads (L2 absorbs; every line fully consumed across waves).
// ---------------------------------------------------------------------------
__global__ __launch_bounds__(256) void wtrans_kernel(const float* __restrict__ wq,
                                                     const float* __restrict__ wk,
                                                     const float* __restrict__ wv,
                                                     const float* __restrict__ wo,
                                                     unsigned short* __restrict__ wt)
{
    int f = (blockIdx.x*256 + threadIdx.x) * 8;        // output bf16 index
    int mat = f >> 18;
    int rem = f & 262143;
    const float* Wm = (mat==0)?wq:(mat==1)?wk:(mat==2)?wv:wo;
    int nn = rem >> 9, kk0 = rem & 511;
    short8 o;
    #pragma unroll
    for (int j=0;j<8;j++)
        o[j] = (short)f2bf(Wm[(size_t)(kk0+j)*512 + nn]);
    *(short8*)(wt + (size_t)mat*262144 + (size_t)nn*512 + kk0) = o;
}

// ---------------------------------------------------------------------------
// Q/K/V projection: X(fp32 [8192][512]) @ W + b.
// z=0 (Q): bf16 [B][H][S][64], pre-scaled by 0.125*log2(e) (exp2 domain).
// z=1 (K): bf16 [B][H][S][64].
// z=2 (V): TRANSPOSED bf16 VT [B][H][64][S].
// ---------------------------------------------------------------------------
__global__ __launch_bounds__(256) void proj_kernel(
    const float* __restrict__ q, const float* __restrict__ k, const float* __restrict__ v,
    const float* __restrict__ bq, const float* __restrict__ bk, const float* __restrict__ bv,
    const unsigned short* __restrict__ wt, unsigned short* __restrict__ outb)
{
    __shared__ uint8_t smem[16384];                    // A: [0,8K), B: [8K,16K)
    const int t = threadIdx.x, l = t&63, w = t>>6, g = l>>4, ln = l&15;
    const int z = blockIdx.z;
    const float* X = (z==0)? q : (z==1)? k : v;
    const float* bias = (z==0)? bq : (z==1)? bk : bv;
    const unsigned short* WTz = wt + (size_t)z*(D_*D_);
    unsigned short* out = outb + (size_t)z*((size_t)B_*H_*S_*64);
    const float scale = (z==0)? 0.18033688011112042f : 1.0f;  // 0.125*log2(e) for Q
    const int m0 = blockIdx.x*128, n0 = blockIdx.y*128;
    uint8_t* As = smem; uint8_t* Bs = smem + 8192;
    const int RB = (w>>1)*64, CB = (w&1)*64;

    const f32x4 zz = {0.f,0.f,0.f,0.f};
    f32x4 acc[4][4];
    #pragma unroll
    for (int i=0;i<4;i++)
        #pragma unroll
        for (int j=0;j<4;j++) acc[i][j] = zz;

    for (int k0=0; k0<D_; k0+=32){
        __syncthreads();
        // stage WT tile [128 n][32 k] via global_load_lds, pre-swizzled source
        #pragma unroll
        for (int i=0;i<2;i++){
            int qc = w + i*4;
            int row = qc*16 + (l>>2);
            int colb = ((l&3)*16) ^ ((row&3)<<4);
            gload_lds16((const uint8_t*)WTz + (((size_t)(n0+row)*D_ + k0)<<1) + colb,
                        Bs + qc*1024);
        }
        // stage X tile [128 m][32 k] fp32->bf16 via cvt_pk, swizzled 16B writes
        #pragma unroll
        for (int i=0;i<2;i++){
            int c = t + i*256;
            int row = c>>2, cc = c&3;
            const float4* src = (const float4*)(X + (size_t)(m0+row)*D_ + k0 + cc*8);
            float4 u0 = src[0], u1 = src[1];
            uint32_t c0,c1,c2,c3;
            asm("v_cvt_pk_bf16_f32 %0, %1, %2" : "=v"(c0) : "v"(u0.x), "v"(u0.y));
            asm("v_cvt_pk_bf16_f32 %0, %1, %2" : "=v"(c1) : "v"(u0.z), "v"(u0.w));
            asm("v_cvt_pk_bf16_f32 %0, %1, %2" : "=v"(c2) : "v"(u1.x), "v"(u1.y));
            asm("v_cvt_pk_bf16_f32 %0, %1, %2" : "=v"(c3) : "v"(u1.z), "v"(u1.w));
            uint4 pk4; pk4.x=c0; pk4.y=c1; pk4.z=c2; pk4.w=c3;
            *(uint4*)(As + row*64 + ((cc*16) ^ ((row&3)<<4))) = pk4;
        }
        __syncthreads();
        short8 af[4], bfr[4];
        #pragma unroll
        for (int ai=0; ai<4; ai++){
            int row = RB + 16*ai + ln;
            af[ai] = *(const short8*)(As + row*64 + ((16*g) ^ ((row&3)<<4)));
        }
        #pragma unroll
        for (int bj=0; bj<4; bj++){
            int row = CB + 16*bj + ln;
            bfr[bj] = *(const short8*)(Bs + row*64 + ((16*g) ^ ((row&3)<<4)));
        }
        #pragma unroll
        for (int ai=0; ai<4; ai++)
            #pragma unroll
            for (int bj=0; bj<4; bj++)
                acc[ai][bj] = MFMA16(af[ai], bfr[bj], acc[ai][bj]);
    }

    if (z == 2){
        // V: write transposed VT[b][gn][s], pack 4 consecutive s (r=0..3) per b64
        #pragma unroll
        for (int bj=0; bj<4; bj++){
            int gn = n0 + CB + 16*bj + ln;           // = h*64 + dep
            float bv2 = bias[gn];
            #pragma unroll
            for (int ai=0; ai<4; ai++){
                int gmb = m0 + RB + 16*ai + 4*g;     // r=0 row
                int bidx = gmb >> 11, s = gmb & 2047;
                u16x4 pk;
                #pragma unroll
                for (int r=0;r<4;r++) pk[r] = f2bf(acc[ai][bj][r] + bv2);
                *(u16x4*)(out + ((size_t)bidx*D_ + gn)*S_ + s) = pk;
            }
        }
    } else {
        // Q/K: bias, scale, write split-head bf16 [B][H][S][64]
        #pragma unroll
        for (int bj=0; bj<4; bj++){
            int gn = n0 + CB + 16*bj + ln;
            float bv2 = bias[gn];
            int h = gn >> 6, dep = gn & 63;
            #pragma unroll
            for (int ai=0; ai<4; ai++){
                #pragma unroll
                for (int r=0;r<4;r++){
                    int gm = m0 + RB + 16*ai + 4*g + r;
                    float val = (acc[ai][bj][r] + bv2) * scale;
                    size_t o = ((size_t)(gm>>11)*H_ + h)*((size_t)S_*64) + (size_t)(gm&2047)*64 + dep;
                    out[o] = f2bf(val);
                }
            }
        }
    }
}

// ---------------------------------------------------------------------------
// Flash attention v3: VALU-lean hot loop.
//  - all LDS addresses hoisted to 2 base regs + ds immediates
//  - zero-shift softmax: p = exp2(st - c), c=0 invariant; guarded cold rescale
//  - lsum accumulated by MFMA with ones B-operand (O-space layout, no shfl)
//  - mask keep via sign-extend bitfield (v_bfe_i32), mask word prefetched
// LDS: K dbuf 2x8K [0,16K), VT dbuf 2x8K [16K,32K), P per-wave 2K [32K,40K)
// ---------------------------------------------------------------------------
__global__ __launch_bounds__(256) void attn_kernel(
    const unsigned short* __restrict__ qb, const unsigned short* __restrict__ kb,
    const unsigned short* __restrict__ vtb, const uint32_t* __restrict__ mb,
    unsigned short* __restrict__ ao)
{
    __shared__ uint8_t smem[40960];
    const int t = threadIdx.x, l = t&63, w = t>>6, g = l>>4, ln = l&15;
    const int bh = blockIdx.y;
    const int b = bh >> 3;
    const int q0 = blockIdx.x * 64;
    const unsigned short* Q  = qb + (size_t)bh*((size_t)S_*64);
    const unsigned short* K  = kb + (size_t)bh*((size_t)S_*64);
    const unsigned short* VT = vtb + ((size_t)b*D_ + (bh&7)*64)*S_;

    // Q fragments; q row for this lane = q0+16w+ln
    const int qrow = q0 + 16*w + ln;
    const short8 qf0 = *(const short8*)(Q + (size_t)qrow*64 + 8*g);
    const short8 qf1 = *(const short8*)(Q + (size_t)qrow*64 + 8*g + 32);

    // hoisted LDS read bases (swizzle folded); K read = b0 + 2048*t4,
    // VT read = b0 + 16384 + 2048*db (b0/b1 re-based per iter by +curb)
    const int Msw = (ln&7)<<4;
    const int sw0 = (16*g) ^ Msw;
    const int sw1 = (16*g + 64) ^ Msw;
    uint8_t* kB0 = smem + (ln*128 + sw0);
    uint8_t* kB1 = smem + (ln*128 + sw1);
    // P region (per-wave, not double-buffered): store/read pointers
    uint8_t* Pw = smem + 32768 + w*2048;
    uint8_t* prd0 = Pw + ln*128 + sw0;
    uint8_t* prd1 = Pw + ln*128 + sw1;

    // staging: 32-bit per-lane source offsets (saddr+voffset form)
    int krow0 = w*8 + (l>>3), krow1 = (w+4)*8 + (l>>3);
    int colb0 = ((l&7)*16) ^ ((krow0&7)<<4);
    int colb1 = ((l&7)*16) ^ ((krow1&7)<<4);
    int kof0 = krow0*128 + colb0,     kof1 = krow1*128 + colb1;
    int vof0 = krow0*(S_*2) + colb0,  vof1 = krow1*(S_*2) + colb1;
    const int ldo0 = w*1024, ldo1 = (w+4)*1024;

    const uint2* mptr = (const uint2*)(mb + ((size_t)b*S_ + qrow)*64);

    const f32x4 zz = {0.f,0.f,0.f,0.f};
    f32x4 O[4], O5 = zz;
    #pragma unroll
    for (int i=0;i<4;i++) O[i] = zz;
    float c = 0.f;                      // softmax shift (stays 0 on hot path)

    const short8 ones = {0x3F80,0x3F80,0x3F80,0x3F80,0x3F80,0x3F80,0x3F80,0x3F80};

    // prologue: stage tile 0 into buffer 0
    gload_lds16((const uint8_t*)K  + kof0, smem + ldo0);
    gload_lds16((const uint8_t*)K  + kof1, smem + ldo1);
    gload_lds16((const uint8_t*)VT + vof0, smem + 16384 + ldo0);
    gload_lds16((const uint8_t*)VT + vof1, smem + 16384 + ldo1);
    kof0 += 8192; kof1 += 8192; vof0 += 128; vof1 += 128;
    int curb = 0;
    uint2 mmc = mptr[0];

    for (int it=0; it<S_/64; ++it){
        __syncthreads();   // staged tile [curb] ready; prior reads of [curb^8192] done
        if (it < S_/64 - 1){
            int nx = curb ^ 8192;
            gload_lds16((const uint8_t*)K  + kof0, smem + nx + ldo0);
            gload_lds16((const uint8_t*)K  + kof1, smem + nx + ldo1);
            gload_lds16((const uint8_t*)VT + vof0, smem + 16384 + nx + ldo0);
            gload_lds16((const uint8_t*)VT + vof1, smem + 16384 + nx + ldo1);
            kof0 += 8192; kof1 += 8192; vof0 += 128; vof1 += 128;
        }
        uint2 mmn = mptr[(it+1)&31];    // prefetch next mask words
        const uint8_t* b0 = kB0 + curb;
        const uint8_t* b1 = kB1 + curb;

        // ST = K @ Q^T -> lane holds ST[kv=16t4+4g+r][q=ln]
        f32x4 st[4];
        __builtin_amdgcn_s_setprio(1);
        #pragma unroll
        for (int t4=0;t4<4;t4++){
            short8 kf0 = *(const short8*)(b0 + 2048*t4);
            short8 kf1 = *(const short8*)(b1 + 2048*t4);
            st[t4] = MFMA16(kf0, qf0, zz);
            st[t4] = MFMA16(kf1, qf1, st[t4]);
        }
        __builtin_amdgcn_s_setprio(0);

        // overflow guard: per-lane max (no shuffles on hot path)
        float m0a = max3f(st[0][0], st[0][1], st[0][2]);
        float m1a = max3f(st[0][3], st[1][0], st[1][1]);
        float m2a = max3f(st[1][2], st[1][3], st[2][0]);
        float m3a = max3f(st[2][1], st[2][2], st[2][3]);
        float m4a = max3f(st[3][0], st[3][1], st[3][2]);
        float lmax = fmaxf(max3f(m0a, m1a, m2a), max3f(m3a, m4a, st[3][3]));
        if (__builtin_expect(__any(lmax > c + 8.0f), 0)){
            // cold path: true row max, rescale accumulators
            float rm = lmax;
            rm = fmaxf(rm, __shfl_xor(rm, 16));
            rm = fmaxf(rm, __shfl_xor(rm, 32));
            float cnew = fmaxf(c, rm);
            float al = __builtin_amdgcn_exp2f(c - cnew);
            c = cnew;
            #pragma unroll
            for (int r=0;r<4;r++){
                float aO = __shfl(al, 4*g + r);
                #pragma unroll
                for (int db=0; db<4; db++) O[db][r] *= aO;
                O5[r] *= aO;
            }
        }

        // p = exp2(st - c), zero masked, pack bf16, b64 P stores
        uint32_t mi0 = (~mmc.x) >> (4*g);
        uint32_t mi1 = (~mmc.y) >> (4*g);
        #pragma unroll
        for (int t4=0;t4<4;t4++){
            uint32_t mi = (t4 >= 2) ? mi1 : mi0;
            const int sh = (t4&1)*16;
            float p0 = maskf(__builtin_amdgcn_exp2f(st[t4][0] - c),
                             (uint32_t)(((int32_t)(mi << (31-(sh+0)))) >> 31));
            float p1 = maskf(__builtin_amdgcn_exp2f(st[t4][1] - c),
                             (uint32_t)(((int32_t)(mi << (31-(sh+1)))) >> 31));
            float p2 = maskf(__builtin_amdgcn_exp2f(st[t4][2] - c),
                             (uint32_t)(((int32_t)(mi << (31-(sh+2)))) >> 31));
            float p3 = maskf(__builtin_amdgcn_exp2f(st[t4][3] - c),
                             (uint32_t)(((int32_t)(mi << (31-(sh+3)))) >> 31));
            uint32_t lo, hi;
            asm("v_cvt_pk_bf16_f32 %0, %1, %2" : "=v"(lo) : "v"(p0), "v"(p1));
            asm("v_cvt_pk_bf16_f32 %0, %1, %2" : "=v"(hi) : "v"(p2), "v"(p3));
            uint2 pk; pk.x = lo; pk.y = hi;
            *(uint2*)(Pw + ln*128 + ((32*t4 + 8*g) ^ Msw)) = pk;
        }
        mmc = mmn;

        // wave-local P write->read fence
        asm volatile("s_waitcnt lgkmcnt(0)" ::: "memory");

        short8 pa0 = *(const short8*)prd0;
        short8 pa1 = *(const short8*)prd1;
        __builtin_amdgcn_s_setprio(1);
        #pragma unroll
        for (int db=0; db<4; db++){
            short8 vf0 = *(const short8*)(b0 + 16384 + 2048*db);
            short8 vf1 = *(const short8*)(b1 + 16384 + 2048*db);
            O[db] = MFMA16(pa0, vf0, O[db]);
            O[db] = MFMA16(pa1, vf1, O[db]);
        }
        // row-sum accumulation via ones-column (lsum in O-space layout)
        O5 = MFMA16(pa0, ones, O5);
        O5 = MFMA16(pa1, ones, O5);
        __builtin_amdgcn_s_setprio(0);
        curb ^= 8192;
    }

    // normalize and write merged-head bf16 [B*S][512]
    #pragma unroll
    for (int r=0;r<4;r++){
        float inv = 1.0f / O5[r];
        int gm = b*S_ + q0 + 16*w + 4*g + r;
        #pragma unroll
        for (int db=0; db<4; db++){
            int col = (bh&7)*64 + 16*db + ln;
            ao[(size_t)gm*D_ + col] = f2bf(O[db][r]*inv);
        }
    }
}

// ---------------------------------------------------------------------------
// Output projection: ao(bf16 [8192][512]) @ wo + bo -> fp32 out
// ---------------------------------------------------------------------------
__global__ __launch_bounds__(256) void outproj_kernel(
    const unsigned short* __restrict__ ao, const unsigned short* __restrict__ wt,
    const float* __restrict__ bo, float* __restrict__ out)
{
    __shared__ uint8_t smem[16384];
    const int t = threadIdx.x, l = t&63, w = t>>6, g = l>>4, ln = l&15;
    const unsigned short* WTz = wt + (size_t)3*(D_*D_);
    const int m0 = blockIdx.x*128, n0 = blockIdx.y*128;
    uint8_t* As = smem; uint8_t* Bs = smem + 8192;
    const int RB = (w>>1)*64, CB = (w&1)*64;

    const f32x4 zz = {0.f,0.f,0.f,0.f};
    f32x4 acc[4][4];
    #pragma unroll
    for (int i=0;i<4;i++)
        #pragma unroll
        for (int j=0;j<4;j++) acc[i][j] = zz;

    for (int k0=0; k0<D_; k0+=32){
        __syncthreads();
        #pragma unroll
        for (int i=0;i<2;i++){
            int qc = w + i*4;
            int row = qc*16 + (l>>2);
            int colb = ((l&3)*16) ^ ((row&3)<<4);
            gload_lds16((const uint8_t*)WTz + (((size_t)(n0+row)*D_ + k0)<<1) + colb,
                        Bs + qc*1024);
            gload_lds16((const uint8_t*)ao + (((size_t)(m0+row)*D_ + k0)<<1) + colb,
                        As + qc*1024);
        }
        __syncthreads();
        short8 af[4], bfr[4];
        #pragma unroll
        for (int ai=0; ai<4; ai++){
            int row = RB + 16*ai + ln;
            af[ai] = *(const short8*)(As + row*64 + ((16*g) ^ ((row&3)<<4)));
        }
        #pragma unroll
        for (int bj=0; bj<4; bj++){
            int row = CB + 16*bj + ln;
            bfr[bj] = *(const short8*)(Bs + row*64 + ((16*g) ^ ((row&3)<<4)));
        }
        #pragma unroll
        for (int ai=0; ai<4; ai++)
            #pragma unroll
            for (int bj=0; bj<4; bj++)
                acc[ai][bj] = MFMA16(af[ai], bfr[bj], acc[ai][bj]);
    }

    #pragma unroll
    for (int bj=0; bj<4; bj++){
        int gn = n0 + CB + 16*bj + ln;
        float bv2 = bo[gn];
        #pragma unroll
        for (int ai=0; ai<4; ai++){
            #pragma unroll
            for (int r=0;r<4;r++){
                int gm = m0 + RB + 16*ai + 4*g + r;
                out[(size_t)gm*D_ + gn] = acc[ai][bj][r] + bv2;
            }
        }
    }
}

// ---------------------------------------------------------------------------
extern "C" void kernel_launch(void* const* d_in, const int* in_sizes, int n_in,
                              void* d_out, int out_size, void* d_ws, size_t ws_size,
                              hipStream_t stream)
{
    const float* q  = (const float*)d_in[0];
    const float* k  = (const float*)d_in[1];
    const float* v  = (const float*)d_in[2];
    const int* mask = (const int*)d_in[3];
    const float* wq = (const float*)d_in[4];
    const float* bq = (const float*)d_in[5];
    const float* wk = (const float*)d_in[6];
    const float* bk = (const float*)d_in[7];
    const float* wv = (const float*)d_in[8];
    const float* bv = (const float*)d_in[9];
    const float* wo = (const float*)d_in[10];
    const float* bo = (const float*)d_in[11];

    uint8_t* ws = (uint8_t*)d_ws;
    // ws layout (bytes):
    //   0        : qb bf16 [B][H][S][64]            (8388608)
    //   8388608  : kb bf16 [B][H][S][64]            (8388608)
    //   16777216 : vt bf16 [B][H][64][S]            (8388608)
    //   25165824 : ao bf16 [8192][512]              (8388608)
    //   33554432 : WT bf16 [4][512][512]            (2097152)
    //   35651584 : mask bits u32 [B*S*64]           (2097152)
    unsigned short* qkvb = (unsigned short*)ws;
    unsigned short* ao   = (unsigned short*)(ws + 25165824);
    unsigned short* wt   = (unsigned short*)(ws + 33554432);
    uint32_t*       mb   = (uint32_t*)      (ws + 35651584);
    float* out = (float*)d_out;

    maskpack_kernel<<<dim3(2048), dim3(256), 0, stream>>>(mask, mb);
    wtrans_kernel<<<dim3(512), dim3(256), 0, stream>>>(wq, wk, wv, wo, wt);
    proj_kernel<<<dim3(64,4,3), dim3(256), 0, stream>>>(q, k, v, bq, bk, bv, wt, qkvb);
    attn_kernel<<<dim3(32,32), dim3(256), 0, stream>>>(qkvb, qkvb + 4194304, qkvb + 8388608, mb, ao);
    outproj_kernel<<<dim3(64,4), dim3(256), 0, stream>>>(ao, wt, bo, out);
}

// Round 5
// 134.971 us; speedup vs baseline: 1.3152x; 1.0418x over previous
//
#include <hip/hip_runtime.h>
#include <hip/hip_bf16.h>
#include <stdint.h>

// Problem constants: B=4, S=2048, D=512, H=8, DEPTH=64
#define B_ 4
#define S_ 2048
#define D_ 512
#define H_ 8

typedef __attribute__((ext_vector_type(8))) short short8;
typedef __attribute__((ext_vector_type(4))) short short4v;
typedef __attribute__((ext_vector_type(4))) float f32x4;
typedef __attribute__((ext_vector_type(4))) unsigned short u16x4;

#define MFMA16(a,b,c) __builtin_amdgcn_mfma_f32_16x16x32_bf16((a),(b),(c),0,0,0)

// K=16 bf16 MFMA: A-operand k = 4*(lane>>4)+j matches swapped-QK^T C quads.
#if __has_builtin(__builtin_amdgcn_mfma_f32_16x16x16bf16_1k)
#define HAVE16K 1
#define MFMA16K(a,b,c) __builtin_amdgcn_mfma_f32_16x16x16bf16_1k((a),(b),(c),0,0,0)
#else
#define HAVE16K 0
#endif

#if __has_builtin(__builtin_amdgcn_sbfe)
#define SBFE1(v, off) ((uint32_t)__builtin_amdgcn_sbfe((int)(v), (off), 1))
#else
#define SBFE1(v, off) ((uint32_t)(((int32_t)((v) << (31-(off)))) >> 31))
#endif

__device__ __forceinline__ unsigned short f2bf(float f){
    return __builtin_bit_cast(unsigned short, __float2bfloat16(f));
}

__device__ __forceinline__ float maskf(float p, uint32_t keep){
    return __builtin_bit_cast(float, __builtin_bit_cast(uint32_t, p) & keep);
}

__device__ __forceinline__ float max3f(float a, float b, float c){
    float d;
    asm("v_max3_f32 %0, %1, %2, %3" : "=v"(d) : "v"(a), "v"(b), "v"(c));
    return d;
}

__device__ __forceinline__ void gload_lds16(const void* g, void* l){
    __builtin_amdgcn_global_load_lds((const __attribute__((address_space(1))) uint32_t*)g,
                                     (__attribute__((address_space(3))) uint32_t*)l, 16, 0, 0);
}

// ---------------------------------------------------------------------------
// Prep 1: pack mask int32 [B][S][S] -> bits [B][S][S/32] (bit=1 means masked)
// ---------------------------------------------------------------------------
__global__ __launch_bounds__(256) void maskpack_kernel(const int* __restrict__ mask,
                                                       uint32_t* __restrict__ out)
{
    int idx = blockIdx.x*256 + threadIdx.x;            // 0 .. B*S*64-1
    const int4* p = (const int4*)(mask + (size_t)idx*32);
    uint32_t bits = 0;
    #pragma unroll
    for (int c=0;c<8;c++){
        int4 v = p[c];
        if (v.x) bits |= 1u << (c*4+0);
        if (v.y) bits |= 1u << (c*4+1);
        if (v.z) bits |= 1u << (c*4+2);
        if (v.w) bits |= 1u << (c*4+3);
    }
    out[idx] = bits;
}

// ---------------------------------------------------------------------------
// Prep 2: WT[mat][n][k] = W[mat][k][n] as bf16 (coalesced reads; 2B scattered
// writes at 1KB stride are absorbed by L2 — wt region is 4MB).
// ---------------------------------------------------------------------------
__global__ __launch_bounds__(256) void wtrans_kernel(const float* __restrict__ wq,
                                                     const float* __restrict__ wk,
                                                     const float* __restrict__ wv,
                                                     const float* __restrict__ wo,
                                                     unsigned short* __restrict__ wt)
{
    int f = blockIdx.x*256 + threadIdx.x;              // 0 .. 4*512*512-1
    int mat = f >> 18;
    int rem = f & 262143;
    const float* Wm = (mat==0)?wq:(mat==1)?wk:(mat==2)?wv:wo;
    int kk = rem >> 9, nn = rem & 511;                 // coalesced read of W[k][n]
    wt[(size_t)mat*262144 + (size_t)nn*512 + kk] = f2bf(Wm[rem]);
}

// ---------------------------------------------------------------------------
// Q/K/V projection: X(fp32 [8192][512]) @ W + b.
// z=0 (Q): bf16 [B][H][S][64], pre-scaled by 0.125*log2(e) (exp2 domain).
// z=1 (K): bf16 [B][H][S][64].
// z=2 (V): VT[b][n][s] directly, via swapped MFMA operands (C = W^T X^T) so
//          the epilogue writes are lane-consecutive in s (coalesced).
// ---------------------------------------------------------------------------
__global__ __launch_bounds__(256) void proj_kernel(
    const float* __restrict__ q, const float* __restrict__ k, const float* __restrict__ v,
    const float* __restrict__ bq, const float* __restrict__ bk, const float* __restrict__ bv,
    const unsigned short* __restrict__ wt, unsigned short* __restrict__ outb)
{
    __shared__ uint8_t smem[16384];                    // A: [0,8K), B: [8K,16K)
    const int t = threadIdx.x, l = t&63, w = t>>6, g = l>>4, ln = l&15;
    const int z = blockIdx.z;
    const float* X = (z==0)? q : (z==1)? k : v;
    const float* bias = (z==0)? bq : (z==1)? bk : bv;
    const unsigned short* WTz = wt + (size_t)z*(D_*D_);
    unsigned short* out = outb + (size_t)z*((size_t)B_*H_*S_*64);
    const float scale = (z==0)? 0.18033688011112042f : 1.0f;  // 0.125*log2(e) for Q
    const int m0 = blockIdx.x*128, n0 = blockIdx.y*128;
    uint8_t* As = smem; uint8_t* Bs = smem + 8192;
    const int RB = (w>>1)*64, CB = (w&1)*64;

    const f32x4 zz = {0.f,0.f,0.f,0.f};
    f32x4 acc[4][4];
    #pragma unroll
    for (int i=0;i<4;i++)
        #pragma unroll
        for (int j=0;j<4;j++) acc[i][j] = zz;

    for (int k0=0; k0<D_; k0+=32){
        __syncthreads();
        // stage WT tile [128 n][32 k] via global_load_lds, pre-swizzled source
        #pragma unroll
        for (int i=0;i<2;i++){
            int qc = w + i*4;
            int row = qc*16 + (l>>2);
            int colb = ((l&3)*16) ^ ((row&3)<<4);
            gload_lds16((const uint8_t*)WTz + (((size_t)(n0+row)*D_ + k0)<<1) + colb,
                        Bs + qc*1024);
        }
        // stage X tile [128 m][32 k] fp32->bf16 via cvt_pk, swizzled 16B writes
        #pragma unroll
        for (int i=0;i<2;i++){
            int c = t + i*256;
            int row = c>>2, cc = c&3;
            const float4* src = (const float4*)(X + (size_t)(m0+row)*D_ + k0 + cc*8);
            float4 u0 = src[0], u1 = src[1];
            uint32_t c0,c1,c2,c3;
            asm("v_cvt_pk_bf16_f32 %0, %1, %2" : "=v"(c0) : "v"(u0.x), "v"(u0.y));
            asm("v_cvt_pk_bf16_f32 %0, %1, %2" : "=v"(c1) : "v"(u0.z), "v"(u0.w));
            asm("v_cvt_pk_bf16_f32 %0, %1, %2" : "=v"(c2) : "v"(u1.x), "v"(u1.y));
            asm("v_cvt_pk_bf16_f32 %0, %1, %2" : "=v"(c3) : "v"(u1.z), "v"(u1.w));
            uint4 pk4; pk4.x=c0; pk4.y=c1; pk4.z=c2; pk4.w=c3;
            *(uint4*)(As + row*64 + ((cc*16) ^ ((row&3)<<4))) = pk4;
        }
        __syncthreads();
        short8 af[4], bfr[4];
        #pragma unroll
        for (int ai=0; ai<4; ai++){
            int row = RB + 16*ai + ln;
            af[ai] = *(const short8*)(As + row*64 + ((16*g) ^ ((row&3)<<4)));
        }
        #pragma unroll
        for (int bj=0; bj<4; bj++){
            int row = CB + 16*bj + ln;
            bfr[bj] = *(const short8*)(Bs + row*64 + ((16*g) ^ ((row&3)<<4)));
        }
        if (z == 2){
            #pragma unroll
            for (int ai=0; ai<4; ai++)
                #pragma unroll
                for (int bj=0; bj<4; bj++)
                    acc[ai][bj] = MFMA16(bfr[bj], af[ai], acc[ai][bj]);
        } else {
            #pragma unroll
            for (int ai=0; ai<4; ai++)
                #pragma unroll
                for (int bj=0; bj<4; bj++)
                    acc[ai][bj] = MFMA16(af[ai], bfr[bj], acc[ai][bj]);
        }
    }

    if (z == 2){
        // acc[ai][bj]: C row = n (CB+16bj+4g+r), C col = m (RB+16ai+ln)
        #pragma unroll
        for (int bj=0; bj<4; bj++){
            #pragma unroll
            for (int ai=0; ai<4; ai++){
                int s = m0 + RB + 16*ai + ln;       // global m: b = s>>11
                #pragma unroll
                for (int r=0;r<4;r++){
                    int gn = n0 + CB + 16*bj + 4*g + r;
                    float val = acc[ai][bj][r] + bias[gn];
                    out[((size_t)(s>>11)*D_ + gn)*S_ + (s&2047)] = f2bf(val);
                }
            }
        }
    } else {
        // Q/K: bias, scale, write split-head bf16 [B][H][S][64]
        #pragma unroll
        for (int bj=0; bj<4; bj++){
            int gn = n0 + CB + 16*bj + ln;
            float bv2 = bias[gn];
            int h = gn >> 6, dep = gn & 63;
            #pragma unroll
            for (int ai=0; ai<4; ai++){
                #pragma unroll
                for (int r=0;r<4;r++){
                    int gm = m0 + RB + 16*ai + 4*g + r;
                    float val = (acc[ai][bj][r] + bv2) * scale;
                    size_t o = ((size_t)(gm>>11)*H_ + h)*((size_t)S_*64) + (size_t)(gm&2047)*64 + dep;
                    out[o] = f2bf(val);
                }
            }
        }
    }
}

// ---------------------------------------------------------------------------
// Flash attention v4: P never touches LDS.
//  - swapped QK^T (16x16x32) -> lane holds score quads kv=16t4+4g+{0..3}
//  - cvt_pk each quad -> bf16 short4 = A-operand of mfma 16x16x16 (K=16)
//  - PV/lsum directly from registers; no P store, no fence, no P reads
//  - zero-shift softmax fast path (c==0), sbfe mask, hoisted LDS addrs
// LDS: K dbuf 2x8K [0,16K), VT dbuf 2x8K [16K,32K)
// ---------------------------------------------------------------------------
__global__ __launch_bounds__(256, 4) void attn_kernel(
    const unsigned short* __restrict__ qb, const unsigned short* __restrict__ kb,
    const unsigned short* __restrict__ vtb, const uint32_t* __restrict__ mb,
    unsigned short* __restrict__ ao)
{
#if HAVE16K
    __shared__ uint8_t smem[32768];
#else
    __shared__ uint8_t smem[40960];
#endif
    const int t = threadIdx.x, l = t&63, w = t>>6, g = l>>4, ln = l&15;
    const int bh = blockIdx.y;
    const int b = bh >> 3;
    const int q0 = blockIdx.x * 64;
    const unsigned short* Q  = qb + (size_t)bh*((size_t)S_*64);
    const unsigned short* K  = kb + (size_t)bh*((size_t)S_*64);
    const unsigned short* VT = vtb + ((size_t)b*D_ + (bh&7)*64)*S_;

    // Q fragments; q row for this lane = q0+16w+ln
    const int qrow = q0 + 16*w + ln;
    const short8 qf0 = *(const short8*)(Q + (size_t)qrow*64 + 8*g);
    const short8 qf1 = *(const short8*)(Q + (size_t)qrow*64 + 8*g + 32);

    // hoisted LDS read bases (swizzle folded)
    const int Msw = (ln&7)<<4;
    const int sw0 = (16*g) ^ Msw;
    const int sw1 = (16*g + 64) ^ Msw;
    uint8_t* kB0 = smem + ln*128 + sw0;           // K b128 reads: +curb +2048*t4
    uint8_t* kB1 = smem + ln*128 + sw1;
#if HAVE16K
    uint8_t* vB  = smem + 16384 + ln*128;         // VT b64 reads: +curb +2048*db +vo[t4]
    const int vo0 = (8*g     ) ^ Msw;
    const int vo1 = (8*g + 32) ^ Msw;
    const int vo2 = (8*g + 64) ^ Msw;
    const int vo3 = (8*g + 96) ^ Msw;
#else
    uint8_t* Pw = smem + 32768 + w*2048;
    uint8_t* prd0 = Pw + ln*128 + sw0;
    uint8_t* prd1 = Pw + ln*128 + sw1;
#endif

    // staging: 32-bit per-lane source offsets
    int krow0 = w*8 + (l>>3), krow1 = (w+4)*8 + (l>>3);
    int colb0 = ((l&7)*16) ^ ((krow0&7)<<4);
    int colb1 = ((l&7)*16) ^ ((krow1&7)<<4);
    int kof0 = krow0*128 + colb0,     kof1 = krow1*128 + colb1;
    int vof0 = krow0*(S_*2) + colb0,  vof1 = krow1*(S_*2) + colb1;
    const int ldo0 = w*1024, ldo1 = (w+4)*1024;

    const uint2* mptr = (const uint2*)(mb + ((size_t)b*S_ + qrow)*64);

    const f32x4 zz = {0.f,0.f,0.f,0.f};
    f32x4 O[4], O5 = zz;
    #pragma unroll
    for (int i=0;i<4;i++) O[i] = zz;
    float c = 0.f;                      // softmax shift (stays 0 on hot path)

    const short4v onesv = {0x3F80,0x3F80,0x3F80,0x3F80};
#if !HAVE16K
    const short8 ones8 = {0x3F80,0x3F80,0x3F80,0x3F80,0x3F80,0x3F80,0x3F80,0x3F80};
#endif

    // prologue: stage tile 0 into buffer 0
    gload_lds16((const uint8_t*)K  + kof0, smem + ldo0);
    gload_lds16((const uint8_t*)K  + kof1, smem + ldo1);
    gload_lds16((const uint8_t*)VT + vof0, smem + 16384 + ldo0);
    gload_lds16((const uint8_t*)VT + vof1, smem + 16384 + ldo1);
    kof0 += 8192; kof1 += 8192; vof0 += 128; vof1 += 128;
    int curb = 0;
    uint2 mmc = mptr[0];

    for (int it=0; it<S_/64; ++it){
        __syncthreads();   // staged tile [curb] ready; prior reads of [curb^8192] done
        if (it < S_/64 - 1){
            int nx = curb ^ 8192;
            gload_lds16((const uint8_t*)K  + kof0, smem + nx + ldo0);
            gload_lds16((const uint8_t*)K  + kof1, smem + nx + ldo1);
            gload_lds16((const uint8_t*)VT + vof0, smem + 16384 + nx + ldo0);
            gload_lds16((const uint8_t*)VT + vof1, smem + 16384 + nx + ldo1);
            kof0 += 8192; kof1 += 8192; vof0 += 128; vof1 += 128;
        }
        uint2 mmn = mptr[(it+1)&31];    // prefetch next mask words
        const uint8_t* b0 = kB0 + curb;
        const uint8_t* b1 = kB1 + curb;

        // ST = K @ Q^T -> lane holds ST[kv=16t4+4g+r][q=ln]
        f32x4 st[4];
        __builtin_amdgcn_s_setprio(1);
        #pragma unroll
        for (int t4=0;t4<4;t4++){
            short8 kf0 = *(const short8*)(b0 + 2048*t4);
            short8 kf1 = *(const short8*)(b1 + 2048*t4);
            st[t4] = MFMA16(kf0, qf0, zz);
            st[t4] = MFMA16(kf1, qf1, st[t4]);
        }
        __builtin_amdgcn_s_setprio(0);

        // overflow guard: per-lane max (no shuffles on hot path)
        float m0a = max3f(st[0][0], st[0][1], st[0][2]);
        float m1a = max3f(st[0][3], st[1][0], st[1][1]);
        float m2a = max3f(st[1][2], st[1][3], st[2][0]);
        float m3a = max3f(st[2][1], st[2][2], st[2][3]);
        float m4a = max3f(st[3][0], st[3][1], st[3][2]);
        float lmax = fmaxf(max3f(m0a, m1a, m2a), max3f(m3a, m4a, st[3][3]));
        if (__builtin_expect(__any(lmax > c + 8.0f), 0)){
            float rm = lmax;
            rm = fmaxf(rm, __shfl_xor(rm, 16));
            rm = fmaxf(rm, __shfl_xor(rm, 32));
            float cnew = fmaxf(c, rm);
            float al = __builtin_amdgcn_exp2f(c - cnew);
            c = cnew;
            #pragma unroll
            for (int r=0;r<4;r++){
                float aO = __shfl(al, 4*g + r);
                #pragma unroll
                for (int db=0; db<4; db++) O[db][r] *= aO;
                O5[r] *= aO;
            }
        }

        // p = exp2(st - c), zero masked, pack to bf16 A-quads
        uint32_t mi0 = (~mmc.x) >> (4*g);
        uint32_t mi1 = (~mmc.y) >> (4*g);
        short4v pa[4];
        auto genp = [&](float cc){
            #pragma unroll
            for (int t4=0;t4<4;t4++){
                uint32_t mi = (t4 >= 2) ? mi1 : mi0;
                const int base = (t4&1)*16;
                float p0 = maskf(__builtin_amdgcn_exp2f(st[t4][0] - cc), SBFE1(mi, base+0));
                float p1 = maskf(__builtin_amdgcn_exp2f(st[t4][1] - cc), SBFE1(mi, base+1));
                float p2 = maskf(__builtin_amdgcn_exp2f(st[t4][2] - cc), SBFE1(mi, base+2));
                float p3 = maskf(__builtin_amdgcn_exp2f(st[t4][3] - cc), SBFE1(mi, base+3));
                uint32_t lo, hi;
                asm("v_cvt_pk_bf16_f32 %0, %1, %2" : "=v"(lo) : "v"(p0), "v"(p1));
                asm("v_cvt_pk_bf16_f32 %0, %1, %2" : "=v"(hi) : "v"(p2), "v"(p3));
                uint2 u; u.x = lo; u.y = hi;
                pa[t4] = __builtin_bit_cast(short4v, u);
            }
        };
        if (__builtin_expect(__all(c == 0.0f), 1)) genp(0.0f); else genp(c);
        mmc = mmn;

#if HAVE16K
        // PV + lsum straight from registers (K=16 MFMAs)
        __builtin_amdgcn_s_setprio(1);
        const uint8_t* vb = vB + curb;
        #pragma unroll
        for (int db=0; db<4; db++){
            short4v vf0 = *(const short4v*)(vb + 2048*db + vo0);
            short4v vf1 = *(const short4v*)(vb + 2048*db + vo1);
            short4v vf2 = *(const short4v*)(vb + 2048*db + vo2);
            short4v vf3 = *(const short4v*)(vb + 2048*db + vo3);
            O[db] = MFMA16K(pa[0], vf0, O[db]);
            O[db] = MFMA16K(pa[1], vf1, O[db]);
            O[db] = MFMA16K(pa[2], vf2, O[db]);
            O[db] = MFMA16K(pa[3], vf3, O[db]);
        }
        O5 = MFMA16K(pa[0], onesv, O5);
        O5 = MFMA16K(pa[1], onesv, O5);
        O5 = MFMA16K(pa[2], onesv, O5);
        O5 = MFMA16K(pa[3], onesv, O5);
        __builtin_amdgcn_s_setprio(0);
#else
        // fallback: P via LDS + 16x16x32 PV
        #pragma unroll
        for (int t4=0;t4<4;t4++){
            uint2 u = __builtin_bit_cast(uint2, pa[t4]);
            *(uint2*)(Pw + ln*128 + ((32*t4 + 8*g) ^ Msw)) = u;
        }
        asm volatile("s_waitcnt lgkmcnt(0)" ::: "memory");
        short8 pa0 = *(const short8*)prd0;
        short8 pa1 = *(const short8*)prd1;
        __builtin_amdgcn_s_setprio(1);
        #pragma unroll
        for (int db=0; db<4; db++){
            int dr = 16*db + ln;
            short8 vf0 = *(const short8*)(smem + 16384 + curb + dr*128 + ((16*g     ) ^ ((dr&7)<<4)));
            short8 vf1 = *(const short8*)(smem + 16384 + curb + dr*128 + ((16*g + 64) ^ ((dr&7)<<4)));
            O[db] = MFMA16(pa0, vf0, O[db]);
            O[db] = MFMA16(pa1, vf1, O[db]);
        }
        O5 = MFMA16(pa0, ones8, O5);
        O5 = MFMA16(pa1, ones8, O5);
        __builtin_amdgcn_s_setprio(0);
#endif
        curb ^= 8192;
    }

    // normalize and write merged-head bf16 [B*S][512]
    #pragma unroll
    for (int r=0;r<4;r++){
        float inv = 1.0f / O5[r];
        int gm = b*S_ + q0 + 16*w + 4*g + r;
        #pragma unroll
        for (int db=0; db<4; db++){
            int col = (bh&7)*64 + 16*db + ln;
            ao[(size_t)gm*D_ + col] = f2bf(O[db][r]*inv);
        }
    }
}

// ---------------------------------------------------------------------------
// Output projection: ao(bf16 [8192][512]) @ wo + bo -> fp32 out
// ---------------------------------------------------------------------------
__global__ __launch_bounds__(256) void outproj_kernel(
    const unsigned short* __restrict__ ao, const unsigned short* __restrict__ wt,
    const float* __restrict__ bo, float* __restrict__ out)
{
    __shared__ uint8_t smem[16384];
    const int t = threadIdx.x, l = t&63, w = t>>6, g = l>>4, ln = l&15;
    const unsigned short* WTz = wt + (size_t)3*(D_*D_);
    const int m0 = blockIdx.x*128, n0 = blockIdx.y*128;
    uint8_t* As = smem; uint8_t* Bs = smem + 8192;
    const int RB = (w>>1)*64, CB = (w&1)*64;

    const f32x4 zz = {0.f,0.f,0.f,0.f};
    f32x4 acc[4][4];
    #pragma unroll
    for (int i=0;i<4;i++)
        #pragma unroll
        for (int j=0;j<4;j++) acc[i][j] = zz;

    for (int k0=0; k0<D_; k0+=32){
        __syncthreads();
        #pragma unroll
        for (int i=0;i<2;i++){
            int qc = w + i*4;
            int row = qc*16 + (l>>2);
            int colb = ((l&3)*16) ^ ((row&3)<<4);
            gload_lds16((const uint8_t*)WTz + (((size_t)(n0+row)*D_ + k0)<<1) + colb,
                        Bs + qc*1024);
            gload_lds16((const uint8_t*)ao + (((size_t)(m0+row)*D_ + k0)<<1) + colb,
                        As + qc*1024);
        }
        __syncthreads();
        short8 af[4], bfr[4];
        #pragma unroll
        for (int ai=0; ai<4; ai++){
            int row = RB + 16*ai + ln;
            af[ai] = *(const short8*)(As + row*64 + ((16*g) ^ ((row&3)<<4)));
        }
        #pragma unroll
        for (int bj=0; bj<4; bj++){
            int row = CB + 16*bj + ln;
            bfr[bj] = *(const short8*)(Bs + row*64 + ((16*g) ^ ((row&3)<<4)));
        }
        #pragma unroll
        for (int ai=0; ai<4; ai++)
            #pragma unroll
            for (int bj=0; bj<4; bj++)
                acc[ai][bj] = MFMA16(af[ai], bfr[bj], acc[ai][bj]);
    }

    #pragma unroll
    for (int bj=0; bj<4; bj++){
        int gn = n0 + CB + 16*bj + ln;
        float bv2 = bo[gn];
        #pragma unroll
        for (int ai=0; ai<4; ai++){
            #pragma unroll
            for (int r=0;r<4;r++){
                int gm = m0 + RB + 16*ai + 4*g + r;
                out[(size_t)gm*D_ + gn] = acc[ai][bj][r] + bv2;
            }
        }
    }
}

// ---------------------------------------------------------------------------
extern "C" void kernel_launch(void* const* d_in, const int* in_sizes, int n_in,
                              void* d_out, int out_size, void* d_ws, size_t ws_size,
                              hipStream_t stream)
{
    const float* q  = (const float*)d_in[0];
    const float* k  = (const float*)d_in[1];
    const float* v  = (const float*)d_in[2];
    const int* mask = (const int*)d_in[3];
    const float* wq = (const float*)d_in[4];
    const float* bq = (const float*)d_in[5];
    const float* wk = (const float*)d_in[6];
    const float* bk = (const float*)d_in[7];
    const float* wv = (const float*)d_in[8];
    const float* bv = (const float*)d_in[9];
    const float* wo = (const float*)d_in[10];
    const float* bo = (const float*)d_in[11];

    uint8_t* ws = (uint8_t*)d_ws;
    // ws layout (bytes):
    //   0        : qb bf16 [B][H][S][64]            (8388608)
    //   8388608  : kb bf16 [B][H][S][64]            (8388608)
    //   16777216 : vt bf16 [B][512][S]              (8388608)
    //   25165824 : ao bf16 [8192][512]              (8388608)
    //   33554432 : WT bf16 [4][512][512]            (2097152)
    //   35651584 : mask bits u32 [B*S*64]           (2097152)
    unsigned short* qkvb = (unsigned short*)ws;
    unsigned short* ao   = (unsigned short*)(ws + 25165824);
    unsigned short* wt   = (unsigned short*)(ws + 33554432);
    uint32_t*       mb   = (uint32_t*)      (ws + 35651584);
    float* out = (float*)d_out;

    maskpack_kernel<<<dim3(2048), dim3(256), 0, stream>>>(mask, mb);
    wtrans_kernel<<<dim3(4096), dim3(256), 0, stream>>>(wq, wk, wv, wo, wt);
    proj_kernel<<<dim3(64,4,3), dim3(256), 0, stream>>>(q, k, v, bq, bk, bv, wt, qkvb);
    attn_kernel<<<dim3(32,32), dim3(256), 0, stream>>>(qkvb, qkvb + 4194304, qkvb + 8388608, mb, ao);
    outproj_kernel<<<dim3(64,4), dim3(256), 0, stream>>>(ao, wt, bo, out);
}

// Round 6
// 134.849 us; speedup vs baseline: 1.3164x; 1.0009x over previous
//
#include <hip/hip_runtime.h>
#include <hip/hip_bf16.h>
#include <stdint.h>

// Problem constants: B=4, S=2048, D=512, H=8, DEPTH=64
#define B_ 4
#define S_ 2048
#define D_ 512
#define H_ 8

typedef __attribute__((ext_vector_type(8))) short short8;
typedef __attribute__((ext_vector_type(4))) short short4v;
typedef __attribute__((ext_vector_type(4))) float f32x4;
typedef __attribute__((ext_vector_type(4))) unsigned short u16x4;

#define MFMA16(a,b,c) __builtin_amdgcn_mfma_f32_16x16x32_bf16((a),(b),(c),0,0,0)

// K=16 bf16 MFMA: A-operand k = 4*(lane>>4)+j matches swapped-QK^T C quads.
#if __has_builtin(__builtin_amdgcn_mfma_f32_16x16x16bf16_1k)
#define HAVE16K 1
#define MFMA16K(a,b,c) __builtin_amdgcn_mfma_f32_16x16x16bf16_1k((a),(b),(c),0,0,0)
#else
#define HAVE16K 0
#endif

#if __has_builtin(__builtin_amdgcn_sbfe)
#define SBFE1(v, off) ((uint32_t)__builtin_amdgcn_sbfe((int)(v), (off), 1))
#else
#define SBFE1(v, off) ((uint32_t)(((int32_t)((v) << (31-(off)))) >> 31))
#endif

__device__ __forceinline__ unsigned short f2bf(float f){
    return __builtin_bit_cast(unsigned short, __float2bfloat16(f));
}

__device__ __forceinline__ float maskf(float p, uint32_t keep){
    return __builtin_bit_cast(float, __builtin_bit_cast(uint32_t, p) & keep);
}

__device__ __forceinline__ float max3f(float a, float b, float c){
    float d;
    asm("v_max3_f32 %0, %1, %2, %3" : "=v"(d) : "v"(a), "v"(b), "v"(c));
    return d;
}

__device__ __forceinline__ void gload_lds16(const void* g, void* l){
    __builtin_amdgcn_global_load_lds((const __attribute__((address_space(1))) uint32_t*)g,
                                     (__attribute__((address_space(3))) uint32_t*)l, 16, 0, 0);
}

// ---------------------------------------------------------------------------
// Prep (merged): blocks [0,4096): WT[mat][n][k] = W[mat][k][n] bf16
//                blocks [4096,6144): mask int32 -> bit-pack (bit=1: masked)
// ---------------------------------------------------------------------------
__global__ __launch_bounds__(256) void prep_kernel(
    const int* __restrict__ mask, uint32_t* __restrict__ mout,
    const float* __restrict__ wq, const float* __restrict__ wk,
    const float* __restrict__ wv, const float* __restrict__ wo,
    unsigned short* __restrict__ wt)
{
    int bid = blockIdx.x;
    if (bid < 4096){
        int f = bid*256 + threadIdx.x;                 // 0 .. 4*512*512-1
        int mat = f >> 18;
        int rem = f & 262143;
        const float* Wm = (mat==0)?wq:(mat==1)?wk:(mat==2)?wv:wo;
        int kk = rem >> 9, nn = rem & 511;             // coalesced read of W[k][n]
        wt[(size_t)mat*262144 + (size_t)nn*512 + kk] = f2bf(Wm[rem]);
    } else {
        int idx = (bid-4096)*256 + threadIdx.x;        // 0 .. B*S*64-1
        const int4* p = (const int4*)(mask + (size_t)idx*32);
        uint32_t bits = 0;
        #pragma unroll
        for (int c=0;c<8;c++){
            int4 v = p[c];
            if (v.x) bits |= 1u << (c*4+0);
            if (v.y) bits |= 1u << (c*4+1);
            if (v.z) bits |= 1u << (c*4+2);
            if (v.w) bits |= 1u << (c*4+3);
        }
        mout[idx] = bits;
    }
}

// ---------------------------------------------------------------------------
// Q/K/V projection: X(fp32 [8192][512]) @ W + b.
// z=0 (Q): bf16 [B][H][S][64], pre-scaled by 0.125*log2(e) (exp2 domain).
// z=1 (K): bf16 [B][H][S][64].
// z=2 (V): VT[b][n][s] via swapped MFMA operands (coalesced epilogue).
// ---------------------------------------------------------------------------
__global__ __launch_bounds__(256) void proj_kernel(
    const float* __restrict__ q, const float* __restrict__ k, const float* __restrict__ v,
    const float* __restrict__ bq, const float* __restrict__ bk, const float* __restrict__ bv,
    const unsigned short* __restrict__ wt, unsigned short* __restrict__ outb)
{
    __shared__ uint8_t smem[16384];                    // A: [0,8K), B: [8K,16K)
    const int t = threadIdx.x, l = t&63, w = t>>6, g = l>>4, ln = l&15;
    const int z = blockIdx.z;
    const float* X = (z==0)? q : (z==1)? k : v;
    const float* bias = (z==0)? bq : (z==1)? bk : bv;
    const unsigned short* WTz = wt + (size_t)z*(D_*D_);
    unsigned short* out = outb + (size_t)z*((size_t)B_*H_*S_*64);
    const float scale = (z==0)? 0.18033688011112042f : 1.0f;  // 0.125*log2(e) for Q
    const int m0 = blockIdx.x*128, n0 = blockIdx.y*128;
    uint8_t* As = smem; uint8_t* Bs = smem + 8192;
    const int RB = (w>>1)*64, CB = (w&1)*64;

    const f32x4 zz = {0.f,0.f,0.f,0.f};
    f32x4 acc[4][4];
    #pragma unroll
    for (int i=0;i<4;i++)
        #pragma unroll
        for (int j=0;j<4;j++) acc[i][j] = zz;

    for (int k0=0; k0<D_; k0+=32){
        __syncthreads();
        #pragma unroll
        for (int i=0;i<2;i++){
            int qc = w + i*4;
            int row = qc*16 + (l>>2);
            int colb = ((l&3)*16) ^ ((row&3)<<4);
            gload_lds16((const uint8_t*)WTz + (((size_t)(n0+row)*D_ + k0)<<1) + colb,
                        Bs + qc*1024);
        }
        #pragma unroll
        for (int i=0;i<2;i++){
            int c = t + i*256;
            int row = c>>2, cc = c&3;
            const float4* src = (const float4*)(X + (size_t)(m0+row)*D_ + k0 + cc*8);
            float4 u0 = src[0], u1 = src[1];
            uint32_t c0,c1,c2,c3;
            asm("v_cvt_pk_bf16_f32 %0, %1, %2" : "=v"(c0) : "v"(u0.x), "v"(u0.y));
            asm("v_cvt_pk_bf16_f32 %0, %1, %2" : "=v"(c1) : "v"(u0.z), "v"(u0.w));
            asm("v_cvt_pk_bf16_f32 %0, %1, %2" : "=v"(c2) : "v"(u1.x), "v"(u1.y));
            asm("v_cvt_pk_bf16_f32 %0, %1, %2" : "=v"(c3) : "v"(u1.z), "v"(u1.w));
            uint4 pk4; pk4.x=c0; pk4.y=c1; pk4.z=c2; pk4.w=c3;
            *(uint4*)(As + row*64 + ((cc*16) ^ ((row&3)<<4))) = pk4;
        }
        __syncthreads();
        short8 af[4], bfr[4];
        #pragma unroll
        for (int ai=0; ai<4; ai++){
            int row = RB + 16*ai + ln;
            af[ai] = *(const short8*)(As + row*64 + ((16*g) ^ ((row&3)<<4)));
        }
        #pragma unroll
        for (int bj=0; bj<4; bj++){
            int row = CB + 16*bj + ln;
            bfr[bj] = *(const short8*)(Bs + row*64 + ((16*g) ^ ((row&3)<<4)));
        }
        if (z == 2){
            #pragma unroll
            for (int ai=0; ai<4; ai++)
                #pragma unroll
                for (int bj=0; bj<4; bj++)
                    acc[ai][bj] = MFMA16(bfr[bj], af[ai], acc[ai][bj]);
        } else {
            #pragma unroll
            for (int ai=0; ai<4; ai++)
                #pragma unroll
                for (int bj=0; bj<4; bj++)
                    acc[ai][bj] = MFMA16(af[ai], bfr[bj], acc[ai][bj]);
        }
    }

    if (z == 2){
        // acc[ai][bj]: C row = n (CB+16bj+4g+r), C col = m (RB+16ai+ln)
        #pragma unroll
        for (int bj=0; bj<4; bj++){
            #pragma unroll
            for (int ai=0; ai<4; ai++){
                int s = m0 + RB + 16*ai + ln;       // global m: b = s>>11
                #pragma unroll
                for (int r=0;r<4;r++){
                    int gn = n0 + CB + 16*bj + 4*g + r;
                    float val = acc[ai][bj][r] + bias[gn];
                    out[((size_t)(s>>11)*D_ + gn)*S_ + (s&2047)] = f2bf(val);
                }
            }
        }
    } else {
        #pragma unroll
        for (int bj=0; bj<4; bj++){
            int gn = n0 + CB + 16*bj + ln;
            float bv2 = bias[gn];
            int h = gn >> 6, dep = gn & 63;
            #pragma unroll
            for (int ai=0; ai<4; ai++){
                #pragma unroll
                for (int r=0;r<4;r++){
                    int gm = m0 + RB + 16*ai + 4*g + r;
                    float val = (acc[ai][bj][r] + bv2) * scale;
                    size_t o = ((size_t)(gm>>11)*H_ + h)*((size_t)S_*64) + (size_t)(gm&2047)*64 + dep;
                    out[o] = f2bf(val);
                }
            }
        }
    }
}

// ---------------------------------------------------------------------------
// Flash attention v5: 32 q-rows per wave (two independent streams A/B).
// K/VT LDS tiles read ONCE per wave-iter, serve both streams: LDS traffic
// per unit work halved; in-wave ILP doubled. Block = 128 q (4 waves x 32).
// LDS: K dbuf 2x8K [0,16K), VT dbuf 2x8K [16K,32K).
// ---------------------------------------------------------------------------
__global__ __launch_bounds__(256, 2) void attn_kernel(
    const unsigned short* __restrict__ qb, const unsigned short* __restrict__ kb,
    const unsigned short* __restrict__ vtb, const uint32_t* __restrict__ mb,
    unsigned short* __restrict__ ao)
{
    __shared__ uint8_t smem[32768];
    const int t = threadIdx.x, l = t&63, w = t>>6, g = l>>4, ln = l&15;
    const int bh = blockIdx.y;
    const int b = bh >> 3;
    const int q0 = blockIdx.x * 128;
    const unsigned short* Q  = qb + (size_t)bh*((size_t)S_*64);
    const unsigned short* K  = kb + (size_t)bh*((size_t)S_*64);
    const unsigned short* VT = vtb + ((size_t)b*D_ + (bh&7)*64)*S_;

    // two q rows per lane: A = q0+32w+ln, B = A+16
    const int qrowA = q0 + 32*w + ln;
    const int qrowB = qrowA + 16;
    const short8 qf0A = *(const short8*)(Q + (size_t)qrowA*64 + 8*g);
    const short8 qf1A = *(const short8*)(Q + (size_t)qrowA*64 + 8*g + 32);
    const short8 qf0B = *(const short8*)(Q + (size_t)qrowB*64 + 8*g);
    const short8 qf1B = *(const short8*)(Q + (size_t)qrowB*64 + 8*g + 32);

    // hoisted LDS read bases (swizzle folded)
    const int Msw = (ln&7)<<4;
    const int sw0 = (16*g) ^ Msw;
    const int sw1 = (16*g + 64) ^ Msw;
    uint8_t* kB0 = smem + ln*128 + sw0;           // K b128 reads: +curb +2048*t4
    uint8_t* kB1 = smem + ln*128 + sw1;
#if HAVE16K
    uint8_t* vB  = smem + 16384 + ln*128;         // VT b64 reads
    const int vo0 = (8*g     ) ^ Msw;
    const int vo1 = (8*g + 32) ^ Msw;
    const int vo2 = (8*g + 64) ^ Msw;
    const int vo3 = (8*g + 96) ^ Msw;
#endif

    // staging: 32-bit per-lane source offsets
    int krow0 = w*8 + (l>>3), krow1 = (w+4)*8 + (l>>3);
    int colb0 = ((l&7)*16) ^ ((krow0&7)<<4);
    int colb1 = ((l&7)*16) ^ ((krow1&7)<<4);
    int kof0 = krow0*128 + colb0,     kof1 = krow1*128 + colb1;
    int vof0 = krow0*(S_*2) + colb0,  vof1 = krow1*(S_*2) + colb1;
    const int ldo0 = w*1024, ldo1 = (w+4)*1024;

    const uint2* mptrA = (const uint2*)(mb + ((size_t)b*S_ + qrowA)*64);
    const uint2* mptrB = (const uint2*)(mb + ((size_t)b*S_ + qrowB)*64);

    const f32x4 zz = {0.f,0.f,0.f,0.f};
    f32x4 OA[4], OB[4], O5A = zz, O5B = zz;
    #pragma unroll
    for (int i=0;i<4;i++){ OA[i] = zz; OB[i] = zz; }
    float cA = 0.f, cB = 0.f;           // softmax shifts (stay 0 on hot path)

    const short4v onesv = {0x3F80,0x3F80,0x3F80,0x3F80};

    // prologue: stage tile 0 into buffer 0
    gload_lds16((const uint8_t*)K  + kof0, smem + ldo0);
    gload_lds16((const uint8_t*)K  + kof1, smem + ldo1);
    gload_lds16((const uint8_t*)VT + vof0, smem + 16384 + ldo0);
    gload_lds16((const uint8_t*)VT + vof1, smem + 16384 + ldo1);
    kof0 += 8192; kof1 += 8192; vof0 += 128; vof1 += 128;
    int curb = 0;
    uint2 mmA = mptrA[0], mmB = mptrB[0];

    for (int it=0; it<S_/64; ++it){
        __syncthreads();   // staged tile [curb] ready; prior reads of [curb^8192] done
        if (it < S_/64 - 1){
            int nx = curb ^ 8192;
            gload_lds16((const uint8_t*)K  + kof0, smem + nx + ldo0);
            gload_lds16((const uint8_t*)K  + kof1, smem + nx + ldo1);
            gload_lds16((const uint8_t*)VT + vof0, smem + 16384 + nx + ldo0);
            gload_lds16((const uint8_t*)VT + vof1, smem + 16384 + nx + ldo1);
            kof0 += 8192; kof1 += 8192; vof0 += 128; vof1 += 128;
        }
        uint2 mnA = mptrA[(it+1)&31], mnB = mptrB[(it+1)&31];
        const uint8_t* b0 = kB0 + curb;
        const uint8_t* b1 = kB1 + curb;

        // ST = K @ Q^T for both q-streams; K fragments read once
        f32x4 stA[4], stB[4];
        __builtin_amdgcn_s_setprio(1);
        #pragma unroll
        for (int t4=0;t4<4;t4++){
            short8 kf0 = *(const short8*)(b0 + 2048*t4);
            short8 kf1 = *(const short8*)(b1 + 2048*t4);
            stA[t4] = MFMA16(kf0, qf0A, zz);
            stB[t4] = MFMA16(kf0, qf0B, zz);
            stA[t4] = MFMA16(kf1, qf1A, stA[t4]);
            stB[t4] = MFMA16(kf1, qf1B, stB[t4]);
        }
        __builtin_amdgcn_s_setprio(0);

        // overflow guards: per-lane max trees, no shuffles on hot path
        float a0 = max3f(stA[0][0], stA[0][1], stA[0][2]);
        float a1 = max3f(stA[0][3], stA[1][0], stA[1][1]);
        float a2 = max3f(stA[1][2], stA[1][3], stA[2][0]);
        float a3 = max3f(stA[2][1], stA[2][2], stA[2][3]);
        float a4 = max3f(stA[3][0], stA[3][1], stA[3][2]);
        float lmaxA = fmaxf(max3f(a0,a1,a2), max3f(a3,a4,stA[3][3]));
        float b0m = max3f(stB[0][0], stB[0][1], stB[0][2]);
        float b1m = max3f(stB[0][3], stB[1][0], stB[1][1]);
        float b2m = max3f(stB[1][2], stB[1][3], stB[2][0]);
        float b3m = max3f(stB[2][1], stB[2][2], stB[2][3]);
        float b4m = max3f(stB[3][0], stB[3][1], stB[3][2]);
        float lmaxB = fmaxf(max3f(b0m,b1m,b2m), max3f(b3m,b4m,stB[3][3]));

        if (__builtin_expect(__any(fmaxf(lmaxA - cA, lmaxB - cB) > 8.0f), 0)){
            float rmA = lmaxA;
            rmA = fmaxf(rmA, __shfl_xor(rmA, 16));
            rmA = fmaxf(rmA, __shfl_xor(rmA, 32));
            float cAn = fmaxf(cA, rmA);
            float alA = __builtin_amdgcn_exp2f(cA - cAn);
            cA = cAn;
            float rmB = lmaxB;
            rmB = fmaxf(rmB, __shfl_xor(rmB, 16));
            rmB = fmaxf(rmB, __shfl_xor(rmB, 32));
            float cBn = fmaxf(cB, rmB);
            float alB = __builtin_amdgcn_exp2f(cB - cBn);
            cB = cBn;
            #pragma unroll
            for (int r=0;r<4;r++){
                float aO = __shfl(alA, 4*g + r);
                float bO = __shfl(alB, 4*g + r);
                #pragma unroll
                for (int db=0; db<4; db++){ OA[db][r] *= aO; OB[db][r] *= bO; }
                O5A[r] *= aO; O5B[r] *= bO;
            }
        }

        // p = exp2(st - c), zero masked, pack to bf16 A-quads
        short4v paA[4], paB[4];
        {
            uint32_t mi0 = (~mmA.x) >> (4*g);
            uint32_t mi1 = (~mmA.y) >> (4*g);
            #pragma unroll
            for (int t4=0;t4<4;t4++){
                uint32_t mi = (t4 >= 2) ? mi1 : mi0;
                const int base = (t4&1)*16;
                float p0 = maskf(__builtin_amdgcn_exp2f(stA[t4][0] - cA), SBFE1(mi, base+0));
                float p1 = maskf(__builtin_amdgcn_exp2f(stA[t4][1] - cA), SBFE1(mi, base+1));
                float p2 = maskf(__builtin_amdgcn_exp2f(stA[t4][2] - cA), SBFE1(mi, base+2));
                float p3 = maskf(__builtin_amdgcn_exp2f(stA[t4][3] - cA), SBFE1(mi, base+3));
                uint32_t lo, hi;
                asm("v_cvt_pk_bf16_f32 %0, %1, %2" : "=v"(lo) : "v"(p0), "v"(p1));
                asm("v_cvt_pk_bf16_f32 %0, %1, %2" : "=v"(hi) : "v"(p2), "v"(p3));
                uint2 u; u.x = lo; u.y = hi;
                paA[t4] = __builtin_bit_cast(short4v, u);
            }
        }
        {
            uint32_t mi0 = (~mmB.x) >> (4*g);
            uint32_t mi1 = (~mmB.y) >> (4*g);
            #pragma unroll
            for (int t4=0;t4<4;t4++){
                uint32_t mi = (t4 >= 2) ? mi1 : mi0;
                const int base = (t4&1)*16;
                float p0 = maskf(__builtin_amdgcn_exp2f(stB[t4][0] - cB), SBFE1(mi, base+0));
                float p1 = maskf(__builtin_amdgcn_exp2f(stB[t4][1] - cB), SBFE1(mi, base+1));
                float p2 = maskf(__builtin_amdgcn_exp2f(stB[t4][2] - cB), SBFE1(mi, base+2));
                float p3 = maskf(__builtin_amdgcn_exp2f(stB[t4][3] - cB), SBFE1(mi, base+3));
                uint32_t lo, hi;
                asm("v_cvt_pk_bf16_f32 %0, %1, %2" : "=v"(lo) : "v"(p0), "v"(p1));
                asm("v_cvt_pk_bf16_f32 %0, %1, %2" : "=v"(hi) : "v"(p2), "v"(p3));
                uint2 u; u.x = lo; u.y = hi;
                paB[t4] = __builtin_bit_cast(short4v, u);
            }
        }
        mmA = mnA; mmB = mnB;

#if HAVE16K
        // PV + lsum for both streams; VT fragments read once
        __builtin_amdgcn_s_setprio(1);
        const uint8_t* vb = vB + curb;
        #pragma unroll
        for (int db=0; db<4; db++){
            short4v vf0 = *(const short4v*)(vb + 2048*db + vo0);
            short4v vf1 = *(const short4v*)(vb + 2048*db + vo1);
            short4v vf2 = *(const short4v*)(vb + 2048*db + vo2);
            short4v vf3 = *(const short4v*)(vb + 2048*db + vo3);
            OA[db] = MFMA16K(paA[0], vf0, OA[db]);
            OB[db] = MFMA16K(paB[0], vf0, OB[db]);
            OA[db] = MFMA16K(paA[1], vf1, OA[db]);
            OB[db] = MFMA16K(paB[1], vf1, OB[db]);
            OA[db] = MFMA16K(paA[2], vf2, OA[db]);
            OB[db] = MFMA16K(paB[2], vf2, OB[db]);
            OA[db] = MFMA16K(paA[3], vf3, OA[db]);
            OB[db] = MFMA16K(paB[3], vf3, OB[db]);
        }
        #pragma unroll
        for (int t4=0;t4<4;t4++){
            O5A = MFMA16K(paA[t4], onesv, O5A);
            O5B = MFMA16K(paB[t4], onesv, O5B);
        }
        __builtin_amdgcn_s_setprio(0);
#else
        // (fallback never used on gfx950)
#endif
        curb ^= 8192;
    }

    // normalize and write merged-head bf16 [B*S][512]
    #pragma unroll
    for (int r=0;r<4;r++){
        float invA = 1.0f / O5A[r];
        float invB = 1.0f / O5B[r];
        int gmA = b*S_ + q0 + 32*w + 4*g + r;
        int gmB = gmA + 16;
        #pragma unroll
        for (int db=0; db<4; db++){
            int col = (bh&7)*64 + 16*db + ln;
            ao[(size_t)gmA*D_ + col] = f2bf(OA[db][r]*invA);
            ao[(size_t)gmB*D_ + col] = f2bf(OB[db][r]*invB);
        }
    }
}

// ---------------------------------------------------------------------------
// Output projection: ao(bf16 [8192][512]) @ wo + bo -> fp32 out
// ---------------------------------------------------------------------------
__global__ __launch_bounds__(256) void outproj_kernel(
    const unsigned short* __restrict__ ao, const unsigned short* __restrict__ wt,
    const float* __restrict__ bo, float* __restrict__ out)
{
    __shared__ uint8_t smem[16384];
    const int t = threadIdx.x, l = t&63, w = t>>6, g = l>>4, ln = l&15;
    const unsigned short* WTz = wt + (size_t)3*(D_*D_);
    const int m0 = blockIdx.x*128, n0 = blockIdx.y*128;
    uint8_t* As = smem; uint8_t* Bs = smem + 8192;
    const int RB = (w>>1)*64, CB = (w&1)*64;

    const f32x4 zz = {0.f,0.f,0.f,0.f};
    f32x4 acc[4][4];
    #pragma unroll
    for (int i=0;i<4;i++)
        #pragma unroll
        for (int j=0;j<4;j++) acc[i][j] = zz;

    for (int k0=0; k0<D_; k0+=32){
        __syncthreads();
        #pragma unroll
        for (int i=0;i<2;i++){
            int qc = w + i*4;
            int row = qc*16 + (l>>2);
            int colb = ((l&3)*16) ^ ((row&3)<<4);
            gload_lds16((const uint8_t*)WTz + (((size_t)(n0+row)*D_ + k0)<<1) + colb,
                        Bs + qc*1024);
            gload_lds16((const uint8_t*)ao + (((size_t)(m0+row)*D_ + k0)<<1) + colb,
                        As + qc*1024);
        }
        __syncthreads();
        short8 af[4], bfr[4];
        #pragma unroll
        for (int ai=0; ai<4; ai++){
            int row = RB + 16*ai + ln;
            af[ai] = *(const short8*)(As + row*64 + ((16*g) ^ ((row&3)<<4)));
        }
        #pragma unroll
        for (int bj=0; bj<4; bj++){
            int row = CB + 16*bj + ln;
            bfr[bj] = *(const short8*)(Bs + row*64 + ((16*g) ^ ((row&3)<<4)));
        }
        #pragma unroll
        for (int ai=0; ai<4; ai++)
            #pragma unroll
            for (int bj=0; bj<4; bj++)
                acc[ai][bj] = MFMA16(af[ai], bfr[bj], acc[ai][bj]);
    }

    #pragma unroll
    for (int bj=0; bj<4; bj++){
        int gn = n0 + CB + 16*bj + ln;
        float bv2 = bo[gn];
        #pragma unroll
        for (int ai=0; ai<4; ai++){
            #pragma unroll
            for (int r=0;r<4;r++){
                int gm = m0 + RB + 16*ai + 4*g + r;
                out[(size_t)gm*D_ + gn] = acc[ai][bj][r] + bv2;
            }
        }
    }
}

// ---------------------------------------------------------------------------
extern "C" void kernel_launch(void* const* d_in, const int* in_sizes, int n_in,
                              void* d_out, int out_size, void* d_ws, size_t ws_size,
                              hipStream_t stream)
{
    const float* q  = (const float*)d_in[0];
    const float* k  = (const float*)d_in[1];
    const float* v  = (const float*)d_in[2];
    const int* mask = (const int*)d_in[3];
    const float* wq = (const float*)d_in[4];
    const float* bq = (const float*)d_in[5];
    const float* wk = (const float*)d_in[6];
    const float* bk = (const float*)d_in[7];
    const float* wv = (const float*)d_in[8];
    const float* bv = (const float*)d_in[9];
    const float* wo = (const float*)d_in[10];
    const float* bo = (const float*)d_in[11];

    uint8_t* ws = (uint8_t*)d_ws;
    // ws layout (bytes):
    //   0        : qb bf16 [B][H][S][64]            (8388608)
    //   8388608  : kb bf16 [B][H][S][64]            (8388608)
    //   16777216 : vt bf16 [B][512][S]              (8388608)
    //   25165824 : ao bf16 [8192][512]              (8388608)
    //   33554432 : WT bf16 [4][512][512]            (2097152)
    //   35651584 : mask bits u32 [B*S*64]           (2097152)
    unsigned short* qkvb = (unsigned short*)ws;
    unsigned short* ao   = (unsigned short*)(ws + 25165824);
    unsigned short* wt   = (unsigned short*)(ws + 33554432);
    uint32_t*       mb   = (uint32_t*)      (ws + 35651584);
    float* out = (float*)d_out;

    prep_kernel<<<dim3(6144), dim3(256), 0, stream>>>(mask, mb, wq, wk, wv, wo, wt);
    proj_kernel<<<dim3(64,4,3), dim3(256), 0, stream>>>(q, k, v, bq, bk, bv, wt, qkvb);
    attn_kernel<<<dim3(16,32), dim3(256), 0, stream>>>(qkvb, qkvb + 4194304, qkvb + 8388608, mb, ao);
    outproj_kernel<<<dim3(64,4), dim3(256), 0, stream>>>(ao, wt, bo, out);
}

// Round 7
// 123.826 us; speedup vs baseline: 1.4335x; 1.0890x over previous
//
#include <hip/hip_runtime.h>
#include <hip/hip_bf16.h>
#include <stdint.h>

// Problem constants: B=4, S=2048, D=512, H=8, DEPTH=64
#define B_ 4
#define S_ 2048
#define D_ 512
#define H_ 8

typedef __attribute__((ext_vector_type(8))) short short8;
typedef __attribute__((ext_vector_type(4))) short short4v;
typedef __attribute__((ext_vector_type(4))) float f32x4;
typedef __attribute__((ext_vector_type(4))) unsigned short u16x4;

#define MFMA16(a,b,c) __builtin_amdgcn_mfma_f32_16x16x32_bf16((a),(b),(c),0,0,0)

// K=16 bf16 MFMA: A-operand k = 4*(lane>>4)+j matches swapped-QK^T C quads.
#if __has_builtin(__builtin_amdgcn_mfma_f32_16x16x16bf16_1k)
#define HAVE16K 1
#define MFMA16K(a,b,c) __builtin_amdgcn_mfma_f32_16x16x16bf16_1k((a),(b),(c),0,0,0)
#else
#define HAVE16K 0
#endif

#if __has_builtin(__builtin_amdgcn_sbfe)
#define SBFE1(v, off) ((uint32_t)__builtin_amdgcn_sbfe((int)(v), (off), 1))
#else
#define SBFE1(v, off) ((uint32_t)(((int32_t)((v) << (31-(off)))) >> 31))
#endif

__device__ __forceinline__ unsigned short f2bf(float f){
    return __builtin_bit_cast(unsigned short, __float2bfloat16(f));
}

__device__ __forceinline__ float maskf(float p, uint32_t keep){
    return __builtin_bit_cast(float, __builtin_bit_cast(uint32_t, p) & keep);
}

__device__ __forceinline__ float max3f(float a, float b, float c){
    float d;
    asm("v_max3_f32 %0, %1, %2, %3" : "=v"(d) : "v"(a), "v"(b), "v"(c));
    return d;
}

__device__ __forceinline__ void gload_lds16(const void* g, void* l){
    __builtin_amdgcn_global_load_lds((const __attribute__((address_space(1))) uint32_t*)g,
                                     (__attribute__((address_space(3))) uint32_t*)l, 16, 0, 0);
}

// ---------------------------------------------------------------------------
// Prep (merged): blocks [0,4096): WT[mat][n][k] = W[mat][k][n] bf16
//                blocks [4096,6144): mask int32 -> bit-pack (bit=1: masked)
// ---------------------------------------------------------------------------
__global__ __launch_bounds__(256) void prep_kernel(
    const int* __restrict__ mask, uint32_t* __restrict__ mout,
    const float* __restrict__ wq, const float* __restrict__ wk,
    const float* __restrict__ wv, const float* __restrict__ wo,
    unsigned short* __restrict__ wt)
{
    int bid = blockIdx.x;
    if (bid < 4096){
        int f = bid*256 + threadIdx.x;                 // 0 .. 4*512*512-1
        int mat = f >> 18;
        int rem = f & 262143;
        const float* Wm = (mat==0)?wq:(mat==1)?wk:(mat==2)?wv:wo;
        int kk = rem >> 9, nn = rem & 511;             // coalesced read of W[k][n]
        wt[(size_t)mat*262144 + (size_t)nn*512 + kk] = f2bf(Wm[rem]);
    } else {
        int idx = (bid-4096)*256 + threadIdx.x;        // 0 .. B*S*64-1
        const int4* p = (const int4*)(mask + (size_t)idx*32);
        uint32_t bits = 0;
        #pragma unroll
        for (int c=0;c<8;c++){
            int4 v = p[c];
            if (v.x) bits |= 1u << (c*4+0);
            if (v.y) bits |= 1u << (c*4+1);
            if (v.z) bits |= 1u << (c*4+2);
            if (v.w) bits |= 1u << (c*4+3);
        }
        mout[idx] = bits;
    }
}

// ---------------------------------------------------------------------------
// Q/K/V projection: X(fp32 [8192][512]) @ W + b.  BK=64 (8 k-steps).
// z=0 (Q): bf16 [B][H][S][64], pre-scaled by 0.125*log2(e) (exp2 domain).
// z=1 (K): bf16 [B][H][S][64].
// z=2 (V): VT[b][n][s] via swapped MFMA operands (coalesced epilogue).
// LDS: A [0,16K) 128x64 bf16 swizzled, B [16K,32K).
// ---------------------------------------------------------------------------
__global__ __launch_bounds__(256) void proj_kernel(
    const float* __restrict__ q, const float* __restrict__ k, const float* __restrict__ v,
    const float* __restrict__ bq, const float* __restrict__ bk, const float* __restrict__ bv,
    const unsigned short* __restrict__ wt, unsigned short* __restrict__ outb)
{
    __shared__ uint8_t smem[32768];
    const int t = threadIdx.x, l = t&63, w = t>>6, g = l>>4, ln = l&15;
    const int z = blockIdx.z;
    const float* X = (z==0)? q : (z==1)? k : v;
    const float* bias = (z==0)? bq : (z==1)? bk : bv;
    const unsigned short* WTz = wt + (size_t)z*(D_*D_);
    unsigned short* out = outb + (size_t)z*((size_t)B_*H_*S_*64);
    const float scale = (z==0)? 0.18033688011112042f : 1.0f;  // 0.125*log2(e) for Q
    const int m0 = blockIdx.x*128, n0 = blockIdx.y*128;
    uint8_t* As = smem; uint8_t* Bs = smem + 16384;
    const int RB = (w>>1)*64, CB = (w&1)*64;

    const f32x4 zz = {0.f,0.f,0.f,0.f};
    f32x4 acc[4][4];
    #pragma unroll
    for (int i=0;i<4;i++)
        #pragma unroll
        for (int j=0;j<4;j++) acc[i][j] = zz;

    for (int k0=0; k0<D_; k0+=64){
        __syncthreads();
        // stage WT tile [128 n][64 k] via global_load_lds, pre-swizzled source
        #pragma unroll
        for (int i=0;i<4;i++){
            int qc = w + i*4;                          // 16 chunks of 1KB
            int row = qc*8 + (l>>3);
            int colb = ((l&7)*16) ^ ((row&7)<<4);
            gload_lds16((const uint8_t*)WTz + (((size_t)(n0+row)*D_ + k0)<<1) + colb,
                        Bs + qc*1024);
        }
        // stage X tile [128 m][64 k] fp32->bf16 via cvt_pk, swizzled 16B writes
        #pragma unroll
        for (int i=0;i<4;i++){
            int c = t + i*256;
            int row = c>>3, cc = c&7;
            const float4* src = (const float4*)(X + (size_t)(m0+row)*D_ + k0 + cc*8);
            float4 u0 = src[0], u1 = src[1];
            uint32_t c0,c1,c2,c3;
            asm("v_cvt_pk_bf16_f32 %0, %1, %2" : "=v"(c0) : "v"(u0.x), "v"(u0.y));
            asm("v_cvt_pk_bf16_f32 %0, %1, %2" : "=v"(c1) : "v"(u0.z), "v"(u0.w));
            asm("v_cvt_pk_bf16_f32 %0, %1, %2" : "=v"(c2) : "v"(u1.x), "v"(u1.y));
            asm("v_cvt_pk_bf16_f32 %0, %1, %2" : "=v"(c3) : "v"(u1.z), "v"(u1.w));
            uint4 pk4; pk4.x=c0; pk4.y=c1; pk4.z=c2; pk4.w=c3;
            *(uint4*)(As + row*128 + ((cc*16) ^ ((row&7)<<4))) = pk4;
        }
        __syncthreads();
        #pragma unroll
        for (int kc=0; kc<2; kc++){
            short8 af[4], bfr[4];
            #pragma unroll
            for (int ai=0; ai<4; ai++){
                int row = RB + 16*ai + ln;
                af[ai] = *(const short8*)(As + row*128 + ((16*g + 64*kc) ^ ((row&7)<<4)));
            }
            #pragma unroll
            for (int bj=0; bj<4; bj++){
                int row = CB + 16*bj + ln;
                bfr[bj] = *(const short8*)(Bs + row*128 + ((16*g + 64*kc) ^ ((row&7)<<4)));
            }
            if (z == 2){
                #pragma unroll
                for (int ai=0; ai<4; ai++)
                    #pragma unroll
                    for (int bj=0; bj<4; bj++)
                        acc[ai][bj] = MFMA16(bfr[bj], af[ai], acc[ai][bj]);
            } else {
                #pragma unroll
                for (int ai=0; ai<4; ai++)
                    #pragma unroll
                    for (int bj=0; bj<4; bj++)
                        acc[ai][bj] = MFMA16(af[ai], bfr[bj], acc[ai][bj]);
            }
        }
    }

    if (z == 2){
        // acc[ai][bj]: C row = n (CB+16bj+4g+r), C col = m (RB+16ai+ln)
        #pragma unroll
        for (int bj=0; bj<4; bj++){
            #pragma unroll
            for (int ai=0; ai<4; ai++){
                int s = m0 + RB + 16*ai + ln;       // global m: b = s>>11
                #pragma unroll
                for (int r=0;r<4;r++){
                    int gn = n0 + CB + 16*bj + 4*g + r;
                    float val = acc[ai][bj][r] + bias[gn];
                    out[((size_t)(s>>11)*D_ + gn)*S_ + (s&2047)] = f2bf(val);
                }
            }
        }
    } else {
        #pragma unroll
        for (int bj=0; bj<4; bj++){
            int gn = n0 + CB + 16*bj + ln;
            float bv2 = bias[gn];
            int h = gn >> 6, dep = gn & 63;
            #pragma unroll
            for (int ai=0; ai<4; ai++){
                #pragma unroll
                for (int r=0;r<4;r++){
                    int gm = m0 + RB + 16*ai + 4*g + r;
                    float val = (acc[ai][bj][r] + bv2) * scale;
                    size_t o = ((size_t)(gm>>11)*H_ + h)*((size_t)S_*64) + (size_t)(gm&2047)*64 + dep;
                    out[o] = f2bf(val);
                }
            }
        }
    }
}

// ---------------------------------------------------------------------------
// Flash attention v6: r5 single-stream structure + XCD-aware block remap
// (all 32 q-blocks of a bh land on one XCD -> K/VT L2-resident per XCD).
// P never touches LDS (K=16 PV from registers). 64 q-rows/block, 4 waves.
// LDS: K dbuf 2x8K [0,16K), VT dbuf 2x8K [16K,32K).
// ---------------------------------------------------------------------------
__global__ __launch_bounds__(256, 4) void attn_kernel(
    const unsigned short* __restrict__ qb, const unsigned short* __restrict__ kb,
    const unsigned short* __restrict__ vtb, const uint32_t* __restrict__ mb,
    unsigned short* __restrict__ ao)
{
#if HAVE16K
    __shared__ uint8_t smem[32768];
#else
    __shared__ uint8_t smem[40960];
#endif
    const int t = threadIdx.x, l = t&63, w = t>>6, g = l>>4, ln = l&15;
    // XCD-aware remap: fid%8 = XCD (HW round-robin); pin bh group per XCD.
    const int fid = blockIdx.x + 32*blockIdx.y;      // grid (32,32)
    const int slot = fid >> 3;                       // 0..127
    const int bh = (fid & 7) + 8*(slot >> 5);        // 0..31
    const int q0 = (slot & 31) * 64;
    const int b = bh >> 3;
    const unsigned short* Q  = qb + (size_t)bh*((size_t)S_*64);
    const unsigned short* K  = kb + (size_t)bh*((size_t)S_*64);
    const unsigned short* VT = vtb + ((size_t)b*D_ + (bh&7)*64)*S_;

    // Q fragments; q row for this lane = q0+16w+ln
    const int qrow = q0 + 16*w + ln;
    const short8 qf0 = *(const short8*)(Q + (size_t)qrow*64 + 8*g);
    const short8 qf1 = *(const short8*)(Q + (size_t)qrow*64 + 8*g + 32);

    // hoisted LDS read bases (swizzle folded)
    const int Msw = (ln&7)<<4;
    const int sw0 = (16*g) ^ Msw;
    const int sw1 = (16*g + 64) ^ Msw;
    uint8_t* kB0 = smem + ln*128 + sw0;           // K b128 reads: +curb +2048*t4
    uint8_t* kB1 = smem + ln*128 + sw1;
#if HAVE16K
    uint8_t* vB  = smem + 16384 + ln*128;         // VT b64 reads
    const int vo0 = (8*g     ) ^ Msw;
    const int vo1 = (8*g + 32) ^ Msw;
    const int vo2 = (8*g + 64) ^ Msw;
    const int vo3 = (8*g + 96) ^ Msw;
#else
    uint8_t* Pw = smem + 32768 + w*2048;
    uint8_t* prd0 = Pw + ln*128 + sw0;
    uint8_t* prd1 = Pw + ln*128 + sw1;
#endif

    // staging: 32-bit per-lane source offsets
    int krow0 = w*8 + (l>>3), krow1 = (w+4)*8 + (l>>3);
    int colb0 = ((l&7)*16) ^ ((krow0&7)<<4);
    int colb1 = ((l&7)*16) ^ ((krow1&7)<<4);
    int kof0 = krow0*128 + colb0,     kof1 = krow1*128 + colb1;
    int vof0 = krow0*(S_*2) + colb0,  vof1 = krow1*(S_*2) + colb1;
    const int ldo0 = w*1024, ldo1 = (w+4)*1024;

    const uint2* mptr = (const uint2*)(mb + ((size_t)b*S_ + qrow)*64);

    const f32x4 zz = {0.f,0.f,0.f,0.f};
    f32x4 O[4], O5 = zz;
    #pragma unroll
    for (int i=0;i<4;i++) O[i] = zz;
    float c = 0.f;                      // softmax shift (stays 0 on hot path)

    const short4v onesv = {0x3F80,0x3F80,0x3F80,0x3F80};
#if !HAVE16K
    const short8 ones8 = {0x3F80,0x3F80,0x3F80,0x3F80,0x3F80,0x3F80,0x3F80,0x3F80};
#endif

    // prologue: stage tile 0 into buffer 0
    gload_lds16((const uint8_t*)K  + kof0, smem + ldo0);
    gload_lds16((const uint8_t*)K  + kof1, smem + ldo1);
    gload_lds16((const uint8_t*)VT + vof0, smem + 16384 + ldo0);
    gload_lds16((const uint8_t*)VT + vof1, smem + 16384 + ldo1);
    kof0 += 8192; kof1 += 8192; vof0 += 128; vof1 += 128;
    int curb = 0;
    uint2 mmc = mptr[0];

    for (int it=0; it<S_/64; ++it){
        __syncthreads();   // staged tile [curb] ready; prior reads of [curb^8192] done
        if (it < S_/64 - 1){
            int nx = curb ^ 8192;
            gload_lds16((const uint8_t*)K  + kof0, smem + nx + ldo0);
            gload_lds16((const uint8_t*)K  + kof1, smem + nx + ldo1);
            gload_lds16((const uint8_t*)VT + vof0, smem + 16384 + nx + ldo0);
            gload_lds16((const uint8_t*)VT + vof1, smem + 16384 + nx + ldo1);
            kof0 += 8192; kof1 += 8192; vof0 += 128; vof1 += 128;
        }
        uint2 mmn = mptr[(it+1)&31];    // prefetch next mask words
        const uint8_t* b0 = kB0 + curb;
        const uint8_t* b1 = kB1 + curb;

        // ST = K @ Q^T -> lane holds ST[kv=16t4+4g+r][q=ln]
        f32x4 st[4];
        __builtin_amdgcn_s_setprio(1);
        #pragma unroll
        for (int t4=0;t4<4;t4++){
            short8 kf0 = *(const short8*)(b0 + 2048*t4);
            short8 kf1 = *(const short8*)(b1 + 2048*t4);
            st[t4] = MFMA16(kf0, qf0, zz);
            st[t4] = MFMA16(kf1, qf1, st[t4]);
        }
        __builtin_amdgcn_s_setprio(0);

        // overflow guard: per-lane max (no shuffles on hot path)
        float m0a = max3f(st[0][0], st[0][1], st[0][2]);
        float m1a = max3f(st[0][3], st[1][0], st[1][1]);
        float m2a = max3f(st[1][2], st[1][3], st[2][0]);
        float m3a = max3f(st[2][1], st[2][2], st[2][3]);
        float m4a = max3f(st[3][0], st[3][1], st[3][2]);
        float lmax = fmaxf(max3f(m0a, m1a, m2a), max3f(m3a, m4a, st[3][3]));
        if (__builtin_expect(__any(lmax > c + 8.0f), 0)){
            float rm = lmax;
            rm = fmaxf(rm, __shfl_xor(rm, 16));
            rm = fmaxf(rm, __shfl_xor(rm, 32));
            float cnew = fmaxf(c, rm);
            float al = __builtin_amdgcn_exp2f(c - cnew);
            c = cnew;
            #pragma unroll
            for (int r=0;r<4;r++){
                float aO = __shfl(al, 4*g + r);
                #pragma unroll
                for (int db=0; db<4; db++) O[db][r] *= aO;
                O5[r] *= aO;
            }
        }

        // p = exp2(st - c), zero masked, pack to bf16 A-quads
        uint32_t mi0 = (~mmc.x) >> (4*g);
        uint32_t mi1 = (~mmc.y) >> (4*g);
        short4v pa[4];
        auto genp = [&](float cc){
            #pragma unroll
            for (int t4=0;t4<4;t4++){
                uint32_t mi = (t4 >= 2) ? mi1 : mi0;
                const int base = (t4&1)*16;
                float p0 = maskf(__builtin_amdgcn_exp2f(st[t4][0] - cc), SBFE1(mi, base+0));
                float p1 = maskf(__builtin_amdgcn_exp2f(st[t4][1] - cc), SBFE1(mi, base+1));
                float p2 = maskf(__builtin_amdgcn_exp2f(st[t4][2] - cc), SBFE1(mi, base+2));
                float p3 = maskf(__builtin_amdgcn_exp2f(st[t4][3] - cc), SBFE1(mi, base+3));
                uint32_t lo, hi;
                asm("v_cvt_pk_bf16_f32 %0, %1, %2" : "=v"(lo) : "v"(p0), "v"(p1));
                asm("v_cvt_pk_bf16_f32 %0, %1, %2" : "=v"(hi) : "v"(p2), "v"(p3));
                uint2 u; u.x = lo; u.y = hi;
                pa[t4] = __builtin_bit_cast(short4v, u);
            }
        };
        if (__builtin_expect(__all(c == 0.0f), 1)) genp(0.0f); else genp(c);
        mmc = mmn;

#if HAVE16K
        // PV + lsum straight from registers (K=16 MFMAs)
        __builtin_amdgcn_s_setprio(1);
        const uint8_t* vb = vB + curb;
        #pragma unroll
        for (int db=0; db<4; db++){
            short4v vf0 = *(const short4v*)(vb + 2048*db + vo0);
            short4v vf1 = *(const short4v*)(vb + 2048*db + vo1);
            short4v vf2 = *(const short4v*)(vb + 2048*db + vo2);
            short4v vf3 = *(const short4v*)(vb + 2048*db + vo3);
            O[db] = MFMA16K(pa[0], vf0, O[db]);
            O[db] = MFMA16K(pa[1], vf1, O[db]);
            O[db] = MFMA16K(pa[2], vf2, O[db]);
            O[db] = MFMA16K(pa[3], vf3, O[db]);
        }
        O5 = MFMA16K(pa[0], onesv, O5);
        O5 = MFMA16K(pa[1], onesv, O5);
        O5 = MFMA16K(pa[2], onesv, O5);
        O5 = MFMA16K(pa[3], onesv, O5);
        __builtin_amdgcn_s_setprio(0);
#else
        // fallback: P via LDS + 16x16x32 PV
        #pragma unroll
        for (int t4=0;t4<4;t4++){
            uint2 u = __builtin_bit_cast(uint2, pa[t4]);
            *(uint2*)(Pw + ln*128 + ((32*t4 + 8*g) ^ Msw)) = u;
        }
        asm volatile("s_waitcnt lgkmcnt(0)" ::: "memory");
        short8 pa0 = *(const short8*)prd0;
        short8 pa1 = *(const short8*)prd1;
        __builtin_amdgcn_s_setprio(1);
        #pragma unroll
        for (int db=0; db<4; db++){
            int dr = 16*db + ln;
            short8 vf0 = *(const short8*)(smem + 16384 + curb + dr*128 + ((16*g     ) ^ ((dr&7)<<4)));
            short8 vf1 = *(const short8*)(smem + 16384 + curb + dr*128 + ((16*g + 64) ^ ((dr&7)<<4)));
            O[db] = MFMA16(pa0, vf0, O[db]);
            O[db] = MFMA16(pa1, vf1, O[db]);
        }
        O5 = MFMA16(pa0, ones8, O5);
        O5 = MFMA16(pa1, ones8, O5);
        __builtin_amdgcn_s_setprio(0);
#endif
        curb ^= 8192;
    }

    // normalize and write merged-head bf16 [B*S][512]
    #pragma unroll
    for (int r=0;r<4;r++){
        float inv = 1.0f / O5[r];
        int gm = b*S_ + q0 + 16*w + 4*g + r;
        #pragma unroll
        for (int db=0; db<4; db++){
            int col = (bh&7)*64 + 16*db + ln;
            ao[(size_t)gm*D_ + col] = f2bf(O[db][r]*inv);
        }
    }
}

// ---------------------------------------------------------------------------
// Output projection: ao(bf16 [8192][512]) @ wo + bo -> fp32 out.  BK=64.
// ---------------------------------------------------------------------------
__global__ __launch_bounds__(256) void outproj_kernel(
    const unsigned short* __restrict__ ao, const unsigned short* __restrict__ wt,
    const float* __restrict__ bo, float* __restrict__ out)
{
    __shared__ uint8_t smem[32768];
    const int t = threadIdx.x, l = t&63, w = t>>6, g = l>>4, ln = l&15;
    const unsigned short* WTz = wt + (size_t)3*(D_*D_);
    const int m0 = blockIdx.x*128, n0 = blockIdx.y*128;
    uint8_t* As = smem; uint8_t* Bs = smem + 16384;
    const int RB = (w>>1)*64, CB = (w&1)*64;

    const f32x4 zz = {0.f,0.f,0.f,0.f};
    f32x4 acc[4][4];
    #pragma unroll
    for (int i=0;i<4;i++)
        #pragma unroll
        for (int j=0;j<4;j++) acc[i][j] = zz;

    for (int k0=0; k0<D_; k0+=64){
        __syncthreads();
        #pragma unroll
        for (int i=0;i<4;i++){
            int qc = w + i*4;
            int row = qc*8 + (l>>3);
            int colb = ((l&7)*16) ^ ((row&7)<<4);
            gload_lds16((const uint8_t*)WTz + (((size_t)(n0+row)*D_ + k0)<<1) + colb,
                        Bs + qc*1024);
            gload_lds16((const uint8_t*)ao + (((size_t)(m0+row)*D_ + k0)<<1) + colb,
                        As + qc*1024);
        }
        __syncthreads();
        #pragma unroll
        for (int kc=0; kc<2; kc++){
            short8 af[4], bfr[4];
            #pragma unroll
            for (int ai=0; ai<4; ai++){
                int row = RB + 16*ai + ln;
                af[ai] = *(const short8*)(As + row*128 + ((16*g + 64*kc) ^ ((row&7)<<4)));
            }
            #pragma unroll
            for (int bj=0; bj<4; bj++){
                int row = CB + 16*bj + ln;
                bfr[bj] = *(const short8*)(Bs + row*128 + ((16*g + 64*kc) ^ ((row&7)<<4)));
            }
            #pragma unroll
            for (int ai=0; ai<4; ai++)
                #pragma unroll
                for (int bj=0; bj<4; bj++)
                    acc[ai][bj] = MFMA16(af[ai], bfr[bj], acc[ai][bj]);
        }
    }

    #pragma unroll
    for (int bj=0; bj<4; bj++){
        int gn = n0 + CB + 16*bj + ln;
        float bv2 = bo[gn];
        #pragma unroll
        for (int ai=0; ai<4; ai++){
            #pragma unroll
            for (int r=0;r<4;r++){
                int gm = m0 + RB + 16*ai + 4*g + r;
                out[(size_t)gm*D_ + gn] = acc[ai][bj][r] + bv2;
            }
        }
    }
}

// ---------------------------------------------------------------------------
extern "C" void kernel_launch(void* const* d_in, const int* in_sizes, int n_in,
                              void* d_out, int out_size, void* d_ws, size_t ws_size,
                              hipStream_t stream)
{
    const float* q  = (const float*)d_in[0];
    const float* k  = (const float*)d_in[1];
    const float* v  = (const float*)d_in[2];
    const int* mask = (const int*)d_in[3];
    const float* wq = (const float*)d_in[4];
    const float* bq = (const float*)d_in[5];
    const float* wk = (const float*)d_in[6];
    const float* bk = (const float*)d_in[7];
    const float* wv = (const float*)d_in[8];
    const float* bv = (const float*)d_in[9];
    const float* wo = (const float*)d_in[10];
    const float* bo = (const float*)d_in[11];

    uint8_t* ws = (uint8_t*)d_ws;
    // ws layout (bytes):
    //   0        : qb bf16 [B][H][S][64]            (8388608)
    //   8388608  : kb bf16 [B][H][S][64]            (8388608)
    //   16777216 : vt bf16 [B][512][S]              (8388608)
    //   25165824 : ao bf16 [8192][512]              (8388608)
    //   33554432 : WT bf16 [4][512][512]            (2097152)
    //   35651584 : mask bits u32 [B*S*64]           (2097152)
    unsigned short* qkvb = (unsigned short*)ws;
    unsigned short* ao   = (unsigned short*)(ws + 25165824);
    unsigned short* wt   = (unsigned short*)(ws + 33554432);
    uint32_t*       mb   = (uint32_t*)      (ws + 35651584);
    float* out = (float*)d_out;

    prep_kernel<<<dim3(6144), dim3(256), 0, stream>>>(mask, mb, wq, wk, wv, wo, wt);
    proj_kernel<<<dim3(64,4,3), dim3(256), 0, stream>>>(q, k, v, bq, bk, bv, wt, qkvb);
    attn_kernel<<<dim3(32,32), dim3(256), 0, stream>>>(qkvb, qkvb + 4194304, qkvb + 8388608, mb, ao);
    outproj_kernel<<<dim3(64,4), dim3(256), 0, stream>>>(ao, wt, bo, out);
}

// Round 9
// 120.251 us; speedup vs baseline: 1.4761x; 1.0297x over previous
//
#include <hip/hip_runtime.h>
#include <hip/hip_bf16.h>
#include <stdint.h>

// Problem constants: B=4, S=2048, D=512, H=8, DEPTH=64
#define B_ 4
#define S_ 2048
#define D_ 512
#define H_ 8

typedef __attribute__((ext_vector_type(8))) short short8;
typedef __attribute__((ext_vector_type(4))) short short4v;
typedef __attribute__((ext_vector_type(4))) float f32x4;
typedef __attribute__((ext_vector_type(4))) unsigned short u16x4;

#define MFMA16(a,b,c) __builtin_amdgcn_mfma_f32_16x16x32_bf16((a),(b),(c),0,0,0)
// K=16 bf16 MFMA: A/B-operand k = 4*(lane>>4)+j matches swapped-QK^T C quads.
#define MFMA16K(a,b,c) __builtin_amdgcn_mfma_f32_16x16x16bf16_1k((a),(b),(c),0,0,0)

#if __has_builtin(__builtin_amdgcn_sbfe)
#define SBFE1(v, off) ((uint32_t)__builtin_amdgcn_sbfe((int)(v), (off), 1))
#else
#define SBFE1(v, off) ((uint32_t)(((int32_t)((v) << (31-(off)))) >> 31))
#endif

__device__ __forceinline__ unsigned short f2bf(float f){
    return __builtin_bit_cast(unsigned short, __float2bfloat16(f));
}

__device__ __forceinline__ float maskf(float p, uint32_t keep){
    return __builtin_bit_cast(float, __builtin_bit_cast(uint32_t, p) & keep);
}

__device__ __forceinline__ float max3f(float a, float b, float c){
    float d;
    asm("v_max3_f32 %0, %1, %2, %3" : "=v"(d) : "v"(a), "v"(b), "v"(c));
    return d;
}

__device__ __forceinline__ void gload_lds16(const void* g, void* l){
    __builtin_amdgcn_global_load_lds((const __attribute__((address_space(1))) uint32_t*)g,
                                     (__attribute__((address_space(3))) uint32_t*)l, 16, 0, 0);
}

// ---------------------------------------------------------------------------
// Prep (merged): blocks [0,4096): WT[mat][n][k] = W[mat][k][n] bf16
//                blocks [4096,6144): mask int32 -> bit-pack (bit=1: masked)
// ---------------------------------------------------------------------------
__global__ __launch_bounds__(256) void prep_kernel(
    const int* __restrict__ mask, uint32_t* __restrict__ mout,
    const float* __restrict__ wq, const float* __restrict__ wk,
    const float* __restrict__ wv, const float* __restrict__ wo,
    unsigned short* __restrict__ wt)
{
    int bid = blockIdx.x;
    if (bid < 4096){
        int f = bid*256 + threadIdx.x;                 // 0 .. 4*512*512-1
        int mat = f >> 18;
        int rem = f & 262143;
        const float* Wm = (mat==0)?wq:(mat==1)?wk:(mat==2)?wv:wo;
        int kk = rem >> 9, nn = rem & 511;             // coalesced read of W[k][n]
        wt[(size_t)mat*262144 + (size_t)nn*512 + kk] = f2bf(Wm[rem]);
    } else {
        int idx = (bid-4096)*256 + threadIdx.x;        // 0 .. B*S*64-1
        const int4* p = (const int4*)(mask + (size_t)idx*32);
        uint32_t bits = 0;
        #pragma unroll
        for (int c=0;c<8;c++){
            int4 v = p[c];
            if (v.x) bits |= 1u << (c*4+0);
            if (v.y) bits |= 1u << (c*4+1);
            if (v.z) bits |= 1u << (c*4+2);
            if (v.w) bits |= 1u << (c*4+3);
        }
        mout[idx] = bits;
    }
}

// ---------------------------------------------------------------------------
// Q/K/V projection: X(fp32 [8192][512]) @ W + b.  BK=64 (8 k-steps).
// z=0 (Q): bf16 [B][H][S][64], pre-scaled by 0.125*log2(e) (exp2 domain).
// z=1 (K): bf16 [B][H][S][64].
// z=2 (V): VT[b][n][s'] via swapped MFMA operands. Within each aligned 64-s
//          chunk, kv=16*t4+4*gq+j is stored at e'=32*(t4>>1)+8*gq+4*(t4&1)+j
//          (bijection on [0,64)) so attn PV A-quads are 16B-contiguous.
// ---------------------------------------------------------------------------
__global__ __launch_bounds__(256) void proj_kernel(
    const float* __restrict__ q, const float* __restrict__ k, const float* __restrict__ v,
    const float* __restrict__ bq, const float* __restrict__ bk, const float* __restrict__ bv,
    const unsigned short* __restrict__ wt, unsigned short* __restrict__ outb)
{
    __shared__ uint8_t smem[32768];
    const int t = threadIdx.x, l = t&63, w = t>>6, g = l>>4, ln = l&15;
    const int z = blockIdx.z;
    const float* X = (z==0)? q : (z==1)? k : v;
    const float* bias = (z==0)? bq : (z==1)? bk : bv;
    const unsigned short* WTz = wt + (size_t)z*(D_*D_);
    unsigned short* out = outb + (size_t)z*((size_t)B_*H_*S_*64);
    const float scale = (z==0)? 0.18033688011112042f : 1.0f;  // 0.125*log2(e) for Q
    const int m0 = blockIdx.x*128, n0 = blockIdx.y*128;
    uint8_t* As = smem; uint8_t* Bs = smem + 16384;
    const int RB = (w>>1)*64, CB = (w&1)*64;

    const f32x4 zz = {0.f,0.f,0.f,0.f};
    f32x4 acc[4][4];
    #pragma unroll
    for (int i=0;i<4;i++)
        #pragma unroll
        for (int j=0;j<4;j++) acc[i][j] = zz;

    for (int k0=0; k0<D_; k0+=64){
        __syncthreads();
        // stage WT tile [128 n][64 k] via global_load_lds, pre-swizzled source
        #pragma unroll
        for (int i=0;i<4;i++){
            int qc = w + i*4;                          // 16 chunks of 1KB
            int row = qc*8 + (l>>3);
            int colb = ((l&7)*16) ^ ((row&7)<<4);
            gload_lds16((const uint8_t*)WTz + (((size_t)(n0+row)*D_ + k0)<<1) + colb,
                        Bs + qc*1024);
        }
        // stage X tile [128 m][64 k] fp32->bf16 via cvt_pk, swizzled 16B writes
        #pragma unroll
        for (int i=0;i<4;i++){
            int c = t + i*256;
            int row = c>>3, cc = c&7;
            const float4* src = (const float4*)(X + (size_t)(m0+row)*D_ + k0 + cc*8);
            float4 u0 = src[0], u1 = src[1];
            uint32_t c0,c1,c2,c3;
            asm("v_cvt_pk_bf16_f32 %0, %1, %2" : "=v"(c0) : "v"(u0.x), "v"(u0.y));
            asm("v_cvt_pk_bf16_f32 %0, %1, %2" : "=v"(c1) : "v"(u0.z), "v"(u0.w));
            asm("v_cvt_pk_bf16_f32 %0, %1, %2" : "=v"(c2) : "v"(u1.x), "v"(u1.y));
            asm("v_cvt_pk_bf16_f32 %0, %1, %2" : "=v"(c3) : "v"(u1.z), "v"(u1.w));
            uint4 pk4; pk4.x=c0; pk4.y=c1; pk4.z=c2; pk4.w=c3;
            *(uint4*)(As + row*128 + ((cc*16) ^ ((row&7)<<4))) = pk4;
        }
        __syncthreads();
        #pragma unroll
        for (int kc=0; kc<2; kc++){
            short8 af[4], bfr[4];
            #pragma unroll
            for (int ai=0; ai<4; ai++){
                int row = RB + 16*ai + ln;
                af[ai] = *(const short8*)(As + row*128 + ((16*g + 64*kc) ^ ((row&7)<<4)));
            }
            #pragma unroll
            for (int bj=0; bj<4; bj++){
                int row = CB + 16*bj + ln;
                bfr[bj] = *(const short8*)(Bs + row*128 + ((16*g + 64*kc) ^ ((row&7)<<4)));
            }
            if (z == 2){
                #pragma unroll
                for (int ai=0; ai<4; ai++)
                    #pragma unroll
                    for (int bj=0; bj<4; bj++)
                        acc[ai][bj] = MFMA16(bfr[bj], af[ai], acc[ai][bj]);
            } else {
                #pragma unroll
                for (int ai=0; ai<4; ai++)
                    #pragma unroll
                    for (int bj=0; bj<4; bj++)
                        acc[ai][bj] = MFMA16(af[ai], bfr[bj], acc[ai][bj]);
            }
        }
    }

    if (z == 2){
        // acc[ai][bj]: C row = n (CB+16bj+4g+r), C col = s (RB+16ai+ln).
        // s_local = 16*ai+ln -> t4=ai, gq=ln>>2, j=ln&3;
        // e' = 32*(ai>>1) + 8*(ln>>2) + 4*(ai&1) + (ln&3)
        const int lnperm = 8*(ln>>2) + (ln&3);
        const int bidx = m0 >> 11;                  // whole block in one batch
        const int schunk = (m0 + RB) & 2047;        // 64-aligned
        #pragma unroll
        for (int bj=0; bj<4; bj++){
            #pragma unroll
            for (int ai=0; ai<4; ai++){
                int soff = schunk + 32*(ai>>1) + 4*(ai&1) + lnperm;
                #pragma unroll
                for (int r=0;r<4;r++){
                    int gn = n0 + CB + 16*bj + 4*g + r;
                    float val = acc[ai][bj][r] + bias[gn];
                    out[((size_t)bidx*D_ + gn)*S_ + soff] = f2bf(val);
                }
            }
        }
    } else {
        #pragma unroll
        for (int bj=0; bj<4; bj++){
            int gn = n0 + CB + 16*bj + ln;
            float bv2 = bias[gn];
            int h = gn >> 6, dep = gn & 63;
            #pragma unroll
            for (int ai=0; ai<4; ai++){
                #pragma unroll
                for (int r=0;r<4;r++){
                    int gm = m0 + RB + 16*ai + 4*g + r;
                    float val = (acc[ai][bj][r] + bv2) * scale;
                    size_t o = ((size_t)(gm>>11)*H_ + h)*((size_t)S_*64) + (size_t)(gm&2047)*64 + dep;
                    out[o] = f2bf(val);
                }
            }
        }
    }
}

// ---------------------------------------------------------------------------
// Flash attention v8: all LDS reads are slot-balanced ds_read_b128.
//  - K tile: 8 b128 per wave-iter, slot = g^(ln&7) (balanced)
//  - VT tile: pair-permuted kv layout -> 8 b128 per wave-iter at slots
//    g^(ln&7) and (4+g)^(ln&7) (balanced; was 16 b64 on 2-of-8 slots)
//  - P never touches LDS (K=16 PV from registers); XCD-aware remap
// LDS: K dbuf 2x8K [0,16K), VT dbuf 2x8K [16K,32K).
// ---------------------------------------------------------------------------
__global__ __launch_bounds__(256, 4) void attn_kernel(
    const unsigned short* __restrict__ qb, const unsigned short* __restrict__ kb,
    const unsigned short* __restrict__ vtb, const uint32_t* __restrict__ mb,
    unsigned short* __restrict__ ao)
{
    __shared__ uint8_t smem[32768];
    const int t = threadIdx.x, l = t&63, w = t>>6, g = l>>4, ln = l&15;
    // XCD-aware remap: fid%8 = XCD (HW round-robin); pin bh group per XCD.
    const int fid = blockIdx.x + 32*blockIdx.y;      // grid (32,32)
    const int slot = fid >> 3;                       // 0..127
    const int bh = (fid & 7) + 8*(slot >> 5);        // 0..31
    const int q0 = (slot & 31) * 64;
    const int b = bh >> 3;
    const unsigned short* Q  = qb + (size_t)bh*((size_t)S_*64);
    const unsigned short* K  = kb + (size_t)bh*((size_t)S_*64);
    const unsigned short* VT = vtb + ((size_t)b*D_ + (bh&7)*64)*S_;

    // Q fragments; q row for this lane = q0+16w+ln
    const int qrow = q0 + 16*w + ln;
    const short8 qf0 = *(const short8*)(Q + (size_t)qrow*64 + 8*g);
    const short8 qf1 = *(const short8*)(Q + (size_t)qrow*64 + 8*g + 32);

    // hoisted LDS read bases (swizzle folded)
    const int Msw = (ln&7)<<4;
    const int sw0 = (16*g) ^ Msw;
    const int sw1 = (16*g + 64) ^ Msw;
    uint8_t* kB0 = smem + ln*128 + sw0;           // K b128 reads: +curb +2048*t4
    uint8_t* kB1 = smem + ln*128 + sw1;
    uint8_t* vB  = smem + 16384 + ln*128;         // VT b128 reads (pair layout)
    const int vpo0 = (16*g     ) ^ Msw;           // slot g^(ln&7): t4 pair (0,1)
    const int vpo1 = (16*g + 64) ^ Msw;           // slot (4+g)^(ln&7): pair (2,3)

    // staging: 32-bit per-lane source offsets
    int krow0 = w*8 + (l>>3), krow1 = (w+4)*8 + (l>>3);
    int colb0 = ((l&7)*16) ^ ((krow0&7)<<4);
    int colb1 = ((l&7)*16) ^ ((krow1&7)<<4);
    int kof0 = krow0*128 + colb0,     kof1 = krow1*128 + colb1;
    int vof0 = krow0*(S_*2) + colb0,  vof1 = krow1*(S_*2) + colb1;
    const int ldo0 = w*1024, ldo1 = (w+4)*1024;

    const uint2* mptr = (const uint2*)(mb + ((size_t)b*S_ + qrow)*64);

    const f32x4 zz = {0.f,0.f,0.f,0.f};
    f32x4 O[4], O5 = zz;
    #pragma unroll
    for (int i=0;i<4;i++) O[i] = zz;
    float c = 0.f;                      // softmax shift (stays 0 on hot path)

    const short4v onesv = {0x3F80,0x3F80,0x3F80,0x3F80};

    // prologue: stage tile 0 into buffer 0
    gload_lds16((const uint8_t*)K  + kof0, smem + ldo0);
    gload_lds16((const uint8_t*)K  + kof1, smem + ldo1);
    gload_lds16((const uint8_t*)VT + vof0, smem + 16384 + ldo0);
    gload_lds16((const uint8_t*)VT + vof1, smem + 16384 + ldo1);
    kof0 += 8192; kof1 += 8192; vof0 += 128; vof1 += 128;
    int curb = 0;
    uint2 mmc = mptr[0];

    for (int it=0; it<S_/64; ++it){
        __syncthreads();   // staged tile [curb] ready; prior reads of [curb^8192] done
        if (it < S_/64 - 1){
            int nx = curb ^ 8192;
            gload_lds16((const uint8_t*)K  + kof0, smem + nx + ldo0);
            gload_lds16((const uint8_t*)K  + kof1, smem + nx + ldo1);
            gload_lds16((const uint8_t*)VT + vof0, smem + 16384 + nx + ldo0);
            gload_lds16((const uint8_t*)VT + vof1, smem + 16384 + nx + ldo1);
            kof0 += 8192; kof1 += 8192; vof0 += 128; vof1 += 128;
        }
        uint2 mmn = mptr[(it+1)&31];    // prefetch next mask words
        const uint8_t* b0 = kB0 + curb;
        const uint8_t* b1 = kB1 + curb;

        // ST = K @ Q^T -> lane holds ST[kv=16t4+4g+r][q=ln]
        f32x4 st[4];
        __builtin_amdgcn_s_setprio(1);
        #pragma unroll
        for (int t4=0;t4<4;t4++){
            short8 kf0 = *(const short8*)(b0 + 2048*t4);
            short8 kf1 = *(const short8*)(b1 + 2048*t4);
            st[t4] = MFMA16(kf0, qf0, zz);
            st[t4] = MFMA16(kf1, qf1, st[t4]);
        }
        __builtin_amdgcn_s_setprio(0);

        // overflow guard: per-lane max (no shuffles on hot path)
        float m0a = max3f(st[0][0], st[0][1], st[0][2]);
        float m1a = max3f(st[0][3], st[1][0], st[1][1]);
        float m2a = max3f(st[1][2], st[1][3], st[2][0]);
        float m3a = max3f(st[2][1], st[2][2], st[2][3]);
        float m4a = max3f(st[3][0], st[3][1], st[3][2]);
        float lmax = fmaxf(max3f(m0a, m1a, m2a), max3f(m3a, m4a, st[3][3]));
        if (__builtin_expect(__any(lmax > c + 8.0f), 0)){
            float rm = lmax;
            rm = fmaxf(rm, __shfl_xor(rm, 16));
            rm = fmaxf(rm, __shfl_xor(rm, 32));
            float cnew = fmaxf(c, rm);
            float al = __builtin_amdgcn_exp2f(c - cnew);
            c = cnew;
            #pragma unroll
            for (int r=0;r<4;r++){
                float aO = __shfl(al, 4*g + r);
                #pragma unroll
                for (int db=0; db<4; db++) O[db][r] *= aO;
                O5[r] *= aO;
            }
        }

        // p = exp2(st - c), zero masked, pack to bf16 A-quads
        uint32_t mi0 = (~mmc.x) >> (4*g);
        uint32_t mi1 = (~mmc.y) >> (4*g);
        short4v pa[4];
        auto genp = [&](float cc){
            #pragma unroll
            for (int t4=0;t4<4;t4++){
                uint32_t mi = (t4 >= 2) ? mi1 : mi0;
                const int base = (t4&1)*16;
                float p0 = maskf(__builtin_amdgcn_exp2f(st[t4][0] - cc), SBFE1(mi, base+0));
                float p1 = maskf(__builtin_amdgcn_exp2f(st[t4][1] - cc), SBFE1(mi, base+1));
                float p2 = maskf(__builtin_amdgcn_exp2f(st[t4][2] - cc), SBFE1(mi, base+2));
                float p3 = maskf(__builtin_amdgcn_exp2f(st[t4][3] - cc), SBFE1(mi, base+3));
                uint32_t lo, hi;
                asm("v_cvt_pk_bf16_f32 %0, %1, %2" : "=v"(lo) : "v"(p0), "v"(p1));
                asm("v_cvt_pk_bf16_f32 %0, %1, %2" : "=v"(hi) : "v"(p2), "v"(p3));
                uint2 u; u.x = lo; u.y = hi;
                pa[t4] = __builtin_bit_cast(short4v, u);
            }
        };
        if (__builtin_expect(__all(c == 0.0f), 1)) genp(0.0f); else genp(c);
        mmc = mmn;

        // PV + lsum straight from registers; VT via b128 pair reads
        __builtin_amdgcn_s_setprio(1);
        const uint8_t* vb = vB + curb;
        #pragma unroll
        for (int db=0; db<4; db++){
            short8 vp0 = *(const short8*)(vb + 2048*db + vpo0);
            short8 vp1 = *(const short8*)(vb + 2048*db + vpo1);
            short4v vf0 = {vp0[0],vp0[1],vp0[2],vp0[3]};
            short4v vf1 = {vp0[4],vp0[5],vp0[6],vp0[7]};
            short4v vf2 = {vp1[0],vp1[1],vp1[2],vp1[3]};
            short4v vf3 = {vp1[4],vp1[5],vp1[6],vp1[7]};
            O[db] = MFMA16K(pa[0], vf0, O[db]);
            O[db] = MFMA16K(pa[1], vf1, O[db]);
            O[db] = MFMA16K(pa[2], vf2, O[db]);
            O[db] = MFMA16K(pa[3], vf3, O[db]);
        }
        O5 = MFMA16K(pa[0], onesv, O5);
        O5 = MFMA16K(pa[1], onesv, O5);
        O5 = MFMA16K(pa[2], onesv, O5);
        O5 = MFMA16K(pa[3], onesv, O5);
        __builtin_amdgcn_s_setprio(0);
        curb ^= 8192;
    }

    // normalize and write merged-head bf16 [B*S][512]
    #pragma unroll
    for (int r=0;r<4;r++){
        float inv = 1.0f / O5[r];
        int gm = b*S_ + q0 + 16*w + 4*g + r;
        #pragma unroll
        for (int db=0; db<4; db++){
            int col = (bh&7)*64 + 16*db + ln;
            ao[(size_t)gm*D_ + col] = f2bf(O[db][r]*inv);
        }
    }
}

// ---------------------------------------------------------------------------
// Output projection: ao(bf16 [8192][512]) @ wo + bo -> fp32 out.  BK=64.
// ---------------------------------------------------------------------------
__global__ __launch_bounds__(256) void outproj_kernel(
    const unsigned short* __restrict__ ao, const unsigned short* __restrict__ wt,
    const float* __restrict__ bo, float* __restrict__ out)
{
    __shared__ uint8_t smem[32768];
    const int t = threadIdx.x, l = t&63, w = t>>6, g = l>>4, ln = l&15;
    const unsigned short* WTz = wt + (size_t)3*(D_*D_);
    const int m0 = blockIdx.x*128, n0 = blockIdx.y*128;
    uint8_t* As = smem; uint8_t* Bs = smem + 16384;
    const int RB = (w>>1)*64, CB = (w&1)*64;

    const f32x4 zz = {0.f,0.f,0.f,0.f};
    f32x4 acc[4][4];
    #pragma unroll
    for (int i=0;i<4;i++)
        #pragma unroll
        for (int j=0;j<4;j++) acc[i][j] = zz;

    for (int k0=0; k0<D_; k0+=64){
        __syncthreads();
        #pragma unroll
        for (int i=0;i<4;i++){
            int qc = w + i*4;
            int row = qc*8 + (l>>3);
            int colb = ((l&7)*16) ^ ((row&7)<<4);
            gload_lds16((const uint8_t*)WTz + (((size_t)(n0+row)*D_ + k0)<<1) + colb,
                        Bs + qc*1024);
            gload_lds16((const uint8_t*)ao + (((size_t)(m0+row)*D_ + k0)<<1) + colb,
                        As + qc*1024);
        }
        __syncthreads();
        #pragma unroll
        for (int kc=0; kc<2; kc++){
            short8 af[4], bfr[4];
            #pragma unroll
            for (int ai=0; ai<4; ai++){
                int row = RB + 16*ai + ln;
                af[ai] = *(const short8*)(As + row*128 + ((16*g + 64*kc) ^ ((row&7)<<4)));
            }
            #pragma unroll
            for (int bj=0; bj<4; bj++){
                int row = CB + 16*bj + ln;
                bfr[bj] = *(const short8*)(Bs + row*128 + ((16*g + 64*kc) ^ ((row&7)<<4)));
            }
            #pragma unroll
            for (int ai=0; ai<4; ai++)
                #pragma unroll
                for (int bj=0; bj<4; bj++)
                    acc[ai][bj] = MFMA16(af[ai], bfr[bj], acc[ai][bj]);
        }
    }

    #pragma unroll
    for (int bj=0; bj<4; bj++){
        int gn = n0 + CB + 16*bj + ln;
        float bv2 = bo[gn];
        #pragma unroll
        for (int ai=0; ai<4; ai++){
            #pragma unroll
            for (int r=0;r<4;r++){
                int gm = m0 + RB + 16*ai + 4*g + r;
                out[(size_t)gm*D_ + gn] = acc[ai][bj][r] + bv2;
            }
        }
    }
}

// ---------------------------------------------------------------------------
extern "C" void kernel_launch(void* const* d_in, const int* in_sizes, int n_in,
                              void* d_out, int out_size, void* d_ws, size_t ws_size,
                              hipStream_t stream)
{
    const float* q  = (const float*)d_in[0];
    const float* k  = (const float*)d_in[1];
    const float* v  = (const float*)d_in[2];
    const int* mask = (const int*)d_in[3];
    const float* wq = (const float*)d_in[4];
    const float* bq = (const float*)d_in[5];
    const float* wk = (const float*)d_in[6];
    const float* bk = (const float*)d_in[7];
    const float* wv = (const float*)d_in[8];
    const float* bv = (const float*)d_in[9];
    const float* wo = (const float*)d_in[10];
    const float* bo = (const float*)d_in[11];

    uint8_t* ws = (uint8_t*)d_ws;
    // ws layout (bytes):
    //   0        : qb bf16 [B][H][S][64]            (8388608)
    //   8388608  : kb bf16 [B][H][S][64]            (8388608)
    //   16777216 : vt bf16 [B][512][S] (pair-perm)  (8388608)
    //   25165824 : ao bf16 [8192][512]              (8388608)
    //   33554432 : WT bf16 [4][512][512]            (2097152)
    //   35651584 : mask bits u32 [B*S*64]           (2097152)
    unsigned short* qkvb = (unsigned short*)ws;
    unsigned short* ao   = (unsigned short*)(ws + 25165824);
    unsigned short* wt   = (unsigned short*)(ws + 33554432);
    uint32_t*       mb   = (uint32_t*)      (ws + 35651584);
    float* out = (float*)d_out;

    prep_kernel<<<dim3(6144), dim3(256), 0, stream>>>(mask, mb, wq, wk, wv, wo, wt);
    proj_kernel<<<dim3(64,4,3), dim3(256), 0, stream>>>(q, k, v, bq, bk, bv, wt, qkvb);
    attn_kernel<<<dim3(32,32), dim3(256), 0, stream>>>(qkvb, qkvb + 4194304, qkvb + 8388608, mb, ao);
    outproj_kernel<<<dim3(64,4), dim3(256), 0, stream>>>(ao, wt, bo, out);
}